// Round 1
// baseline (272.615 us; speedup 1.0000x reference)
//
#include <hip/hip_runtime.h>
#include <math.h>

#define BB 8
#define TT 2048
#define DD 32
#define HH 4
#define HD 8
#define NROWS (BB*TT)       // 16384
#define LNEPS 1e-5f

// ---------------- Kernel 1: LN1 + QKV projection ----------------
__global__ __launch_bounds__(256) void k_ln_qkv(
    const float* __restrict__ x,
    const float* __restrict__ Wq, const float* __restrict__ Wk, const float* __restrict__ Wv,
    const float* __restrict__ g, const float* __restrict__ b,
    float* __restrict__ h, float* __restrict__ q,
    float* __restrict__ k, float* __restrict__ v)
{
    __shared__ float sWq[HH*DD*HD], sWk[HH*DD*HD], sWv[HH*DD*HD], sg[DD], sb[DD];
    for (int i = threadIdx.x; i < HH*DD*HD; i += 256) {
        sWq[i] = Wq[i]; sWk[i] = Wk[i]; sWv[i] = Wv[i];
    }
    if (threadIdx.x < DD) { sg[threadIdx.x] = g[threadIdx.x]; sb[threadIdx.x] = b[threadIdx.x]; }
    __syncthreads();

    int r = blockIdx.x * 256 + threadIdx.x;
    if (r >= NROWS) return;

    float xr[DD];
    const float4* xp = (const float4*)(x + (size_t)r * DD);
    #pragma unroll
    for (int i = 0; i < DD/4; ++i) {
        float4 t4 = xp[i];
        xr[4*i] = t4.x; xr[4*i+1] = t4.y; xr[4*i+2] = t4.z; xr[4*i+3] = t4.w;
    }
    float mu = 0.f;
    #pragma unroll
    for (int i = 0; i < DD; ++i) mu += xr[i];
    mu *= (1.f/DD);
    float var = 0.f;
    #pragma unroll
    for (int i = 0; i < DD; ++i) { float d = xr[i]-mu; var += d*d; }
    var *= (1.f/DD);
    float rs = rsqrtf(var + LNEPS);
    float hr[DD];
    #pragma unroll
    for (int i = 0; i < DD; ++i) hr[i] = (xr[i]-mu)*rs*sg[i] + sb[i];

    float4* hp = (float4*)(h + (size_t)r * DD);
    #pragma unroll
    for (int i = 0; i < DD/4; ++i)
        hp[i] = make_float4(hr[4*i], hr[4*i+1], hr[4*i+2], hr[4*i+3]);

    int bb = r / TT, tt = r % TT;
    for (int hh = 0; hh < HH; ++hh) {
        float qa[HD], ka[HD], va[HD];
        #pragma unroll
        for (int kk = 0; kk < HD; ++kk) { qa[kk]=0.f; ka[kk]=0.f; va[kk]=0.f; }
        #pragma unroll
        for (int d = 0; d < DD; ++d) {
            float hv = hr[d];
            #pragma unroll
            for (int kk = 0; kk < HD; ++kk) {
                qa[kk] += hv * sWq[hh*DD*HD + d*HD + kk];
                ka[kk] += hv * sWk[hh*DD*HD + d*HD + kk];
                va[kk] += hv * sWv[hh*DD*HD + d*HD + kk];
            }
        }
        size_t base = ((size_t)(bb*HH + hh) * TT + tt) * HD;
        float4* qp = (float4*)(q + base);
        float4* kp = (float4*)(k + base);
        float4* vp = (float4*)(v + base);
        qp[0] = make_float4(qa[0],qa[1],qa[2],qa[3]);
        qp[1] = make_float4(qa[4],qa[5],qa[6],qa[7]);
        kp[0] = make_float4(ka[0],ka[1],ka[2],ka[3]);
        kp[1] = make_float4(ka[4],ka[5],ka[6],ka[7]);
        vp[0] = make_float4(va[0],va[1],va[2],va[3]);
        vp[1] = make_float4(va[4],va[5],va[6],va[7]);
    }
}

// ---------------- Kernel 2: flash attention, one wave per query row ----------------
__global__ __launch_bounds__(256) void k_attn(
    const float* __restrict__ q, const float* __restrict__ k,
    const float* __restrict__ v, float* __restrict__ o)
{
    int wave = threadIdx.x >> 6;
    int lane = threadIdx.x & 63;
    int gr = blockIdx.x * 4 + wave;          // row index over B*H*T
    int bh = gr / TT, tt = gr % TT;
    const float scale = 0.35355339059327373f; // 1/sqrt(8)

    const float* kb = k + (size_t)bh * TT * HD;
    const float* vb = v + (size_t)bh * TT * HD;

    float qr[HD];
    {
        const float4* qp = (const float4*)(q + ((size_t)bh*TT + tt) * HD);
        float4 a = qp[0], c = qp[1];
        qr[0]=a.x; qr[1]=a.y; qr[2]=a.z; qr[3]=a.w;
        qr[4]=c.x; qr[5]=c.y; qr[6]=c.z; qr[7]=c.w;
    }

    float m = -INFINITY, l = 0.f;
    float acc[HD];
    #pragma unroll
    for (int j = 0; j < HD; ++j) acc[j] = 0.f;

    for (int sc = 0; sc <= tt; sc += 64) {
        int s = sc + lane;
        if (s <= tt) {
            const float4* kp = (const float4*)(kb + (size_t)s * HD);
            float4 k0 = kp[0], k1 = kp[1];
            float score = qr[0]*k0.x + qr[1]*k0.y + qr[2]*k0.z + qr[3]*k0.w
                        + qr[4]*k1.x + qr[5]*k1.y + qr[6]*k1.z + qr[7]*k1.w;
            score *= scale;
            float mn = fmaxf(m, score);
            float corr = __expf(m - mn);     // m=-inf first time -> 0, fine
            float p    = __expf(score - mn);
            l = l * corr + p;
            const float4* vp = (const float4*)(vb + (size_t)s * HD);
            float4 v0 = vp[0], v1 = vp[1];
            acc[0] = acc[0]*corr + p*v0.x;
            acc[1] = acc[1]*corr + p*v0.y;
            acc[2] = acc[2]*corr + p*v0.z;
            acc[3] = acc[3]*corr + p*v0.w;
            acc[4] = acc[4]*corr + p*v1.x;
            acc[5] = acc[5]*corr + p*v1.y;
            acc[6] = acc[6]*corr + p*v1.z;
            acc[7] = acc[7]*corr + p*v1.w;
            m = mn;
        }
    }

    // merge 64 lanes
    float mt = m;
    #pragma unroll
    for (int off = 32; off > 0; off >>= 1) mt = fmaxf(mt, __shfl_xor(mt, off, 64));
    float wsc = (m == -INFINITY) ? 0.f : __expf(m - mt);
    float lt = l * wsc;
    #pragma unroll
    for (int off = 32; off > 0; off >>= 1) lt += __shfl_xor(lt, off, 64);
    float inv = 1.f / lt;

    float outv[HD];
    #pragma unroll
    for (int j = 0; j < HD; ++j) {
        float a = acc[j] * wsc;
        #pragma unroll
        for (int off = 32; off > 0; off >>= 1) a += __shfl_xor(a, off, 64);
        outv[j] = a * inv;
    }
    if (lane == 0) {
        float4* op = (float4*)(o + ((size_t)bh*TT + tt) * HD);
        op[0] = make_float4(outv[0], outv[1], outv[2], outv[3]);
        op[1] = make_float4(outv[4], outv[5], outv[6], outv[7]);
    }
}

// ---------------- Kernel 3: proj + residual + LN2 + FFN + residual ----------------
__global__ __launch_bounds__(256) void k_proj_ffn(
    const float* __restrict__ h, const float* __restrict__ o,
    const float* __restrict__ Wproj, const float* __restrict__ bproj,
    const float* __restrict__ W1, const float* __restrict__ b1,
    const float* __restrict__ W2, const float* __restrict__ b2,
    const float* __restrict__ g2, const float* __restrict__ bt2,
    float* __restrict__ out)
{
    __shared__ float sWp[DD*DD], sW1[DD*4*DD], sW2[4*DD*DD];
    __shared__ float sbp[DD], sb1[4*DD], sb2[DD], sg2[DD], sbt2[DD];
    for (int i = threadIdx.x; i < DD*DD; i += 256) sWp[i] = Wproj[i];
    for (int i = threadIdx.x; i < DD*4*DD; i += 256) { sW1[i] = W1[i]; sW2[i] = W2[i]; }
    if (threadIdx.x < DD) {
        sbp[threadIdx.x] = bproj[threadIdx.x];
        sb2[threadIdx.x] = b2[threadIdx.x];
        sg2[threadIdx.x] = g2[threadIdx.x];
        sbt2[threadIdx.x] = bt2[threadIdx.x];
    }
    if (threadIdx.x < 4*DD) sb1[threadIdx.x] = b1[threadIdx.x];
    __syncthreads();

    int r = blockIdx.x * 256 + threadIdx.x;
    if (r >= NROWS) return;
    int bb = r / TT, tt = r % TT;

    float hr[DD];
    {
        const float4* hp = (const float4*)(h + (size_t)r * DD);
        #pragma unroll
        for (int i = 0; i < DD/4; ++i) {
            float4 t4 = hp[i];
            hr[4*i]=t4.x; hr[4*i+1]=t4.y; hr[4*i+2]=t4.z; hr[4*i+3]=t4.w;
        }
    }
    float o32[DD];
    #pragma unroll
    for (int hh = 0; hh < HH; ++hh) {
        const float4* op = (const float4*)(o + ((size_t)(bb*HH + hh)*TT + tt) * HD);
        float4 a = op[0], c = op[1];
        o32[hh*HD+0]=a.x; o32[hh*HD+1]=a.y; o32[hh*HD+2]=a.z; o32[hh*HD+3]=a.w;
        o32[hh*HD+4]=c.x; o32[hh*HD+5]=c.y; o32[hh*HD+6]=c.z; o32[hh*HD+7]=c.w;
    }

    float x1[DD];
    #pragma unroll
    for (int d = 0; d < DD; ++d) x1[d] = hr[d] + sbp[d];
    for (int j = 0; j < DD; ++j) {
        float ov = o32[j];
        #pragma unroll
        for (int d = 0; d < DD; ++d) x1[d] += ov * sWp[j*DD + d];
    }

    float mu = 0.f;
    #pragma unroll
    for (int d = 0; d < DD; ++d) mu += x1[d];
    mu *= (1.f/DD);
    float var = 0.f;
    #pragma unroll
    for (int d = 0; d < DD; ++d) { float dl = x1[d]-mu; var += dl*dl; }
    var *= (1.f/DD);
    float rs = rsqrtf(var + LNEPS);
    float h2[DD];
    #pragma unroll
    for (int d = 0; d < DD; ++d) h2[d] = (x1[d]-mu)*rs*sg2[d] + sbt2[d];

    float outr[DD];
    #pragma unroll
    for (int d = 0; d < DD; ++d) outr[d] = h2[d] + sb2[d];
    for (int j = 0; j < 4*DD; ++j) {
        float a = sb1[j];
        #pragma unroll
        for (int d = 0; d < DD; ++d) a += h2[d] * sW1[d*4*DD + j];
        a = fmaxf(a, 0.f);
        #pragma unroll
        for (int d = 0; d < DD; ++d) outr[d] += a * sW2[j*DD + d];
    }

    float4* op = (float4*)(out + (size_t)r * DD);
    #pragma unroll
    for (int i = 0; i < DD/4; ++i)
        op[i] = make_float4(outr[4*i], outr[4*i+1], outr[4*i+2], outr[4*i+3]);
}

extern "C" void kernel_launch(void* const* d_in, const int* in_sizes, int n_in,
                              void* d_out, int out_size, void* d_ws, size_t ws_size,
                              hipStream_t stream) {
    const float* x     = (const float*)d_in[0];
    const float* Wq    = (const float*)d_in[1];
    const float* Wk    = (const float*)d_in[2];
    const float* Wv    = (const float*)d_in[3];
    const float* Wproj = (const float*)d_in[4];
    const float* bproj = (const float*)d_in[5];
    const float* ln1_g = (const float*)d_in[6];
    const float* ln1_b = (const float*)d_in[7];
    const float* W1    = (const float*)d_in[8];
    const float* b1    = (const float*)d_in[9];
    const float* W2    = (const float*)d_in[10];
    const float* b2    = (const float*)d_in[11];
    const float* ln2_g = (const float*)d_in[12];
    const float* ln2_b = (const float*)d_in[13];
    float* out = (float*)d_out;

    const size_t N = (size_t)NROWS * DD;   // 524288 floats
    float* ws = (float*)d_ws;
    float* h = ws;
    float* q = ws + N;
    float* k = ws + 2*N;
    float* v = ws + 3*N;
    float* o = ws + 4*N;

    k_ln_qkv<<<(NROWS+255)/256, 256, 0, stream>>>(x, Wq, Wk, Wv, ln1_g, ln1_b, h, q, k, v);
    k_attn<<<(BB*HH*TT)/4, 256, 0, stream>>>(q, k, v, o);
    k_proj_ffn<<<(NROWS+255)/256, 256, 0, stream>>>(h, o, Wproj, bproj, W1, b1, W2, b2, ln2_g, ln2_b, out);
}

// Round 2
// 210.608 us; speedup vs baseline: 1.2944x; 1.2944x over previous
//
#include <hip/hip_runtime.h>
#include <math.h>

#define BB 8
#define TT 2048
#define DD 32
#define HH 4
#define HD 8
#define NROWS (BB*TT)       // 16384
#define LNEPS 1e-5f

#if __has_builtin(__builtin_amdgcn_exp2f)
#define EXP2F(x) __builtin_amdgcn_exp2f(x)
#else
#define EXP2F(x) __expf(0.6931471805599453f*(x))
#endif

// ---------------- Kernel 1: LN1 + QKV projection (4 threads/row, one head each) ----
__global__ __launch_bounds__(256) void k_ln_qkv(
    const float* __restrict__ x,
    const float* __restrict__ Wq, const float* __restrict__ Wk, const float* __restrict__ Wv,
    const float* __restrict__ g, const float* __restrict__ b,
    float* __restrict__ h, float* __restrict__ q, float* __restrict__ kv)
{
    __shared__ float sW[3*HH*DD*HD];   // Wq | Wk | Wv, each [H][D][HD]
    __shared__ float sg[DD], sb[DD];
    for (int i = threadIdx.x; i < HH*DD*HD; i += 256) {
        sW[i]            = Wq[i];
        sW[1024 + i]     = Wk[i];
        sW[2048 + i]     = Wv[i];
    }
    if (threadIdx.x < DD) { sg[threadIdx.x] = g[threadIdx.x]; sb[threadIdx.x] = b[threadIdx.x]; }
    __syncthreads();

    int idx = blockIdx.x * 256 + threadIdx.x;     // 0..65535
    int r   = idx >> 2;                           // row 0..16383
    int hh  = idx & 3;                            // head
    int bb  = r >> 11, tt = r & 2047;

    float xr[DD];
    {
        const float4* xp = (const float4*)(x + (size_t)r * DD);
        #pragma unroll
        for (int i = 0; i < DD/4; ++i) {
            float4 t4 = xp[i];
            xr[4*i]=t4.x; xr[4*i+1]=t4.y; xr[4*i+2]=t4.z; xr[4*i+3]=t4.w;
        }
    }
    float mu = 0.f;
    #pragma unroll
    for (int i = 0; i < DD; ++i) mu += xr[i];
    mu *= (1.f/DD);
    float var = 0.f;
    #pragma unroll
    for (int i = 0; i < DD; ++i) { float d = xr[i]-mu; var += d*d; }
    var *= (1.f/DD);
    float rs = rsqrtf(var + LNEPS);
    float hr[DD];
    #pragma unroll
    for (int i = 0; i < DD; ++i) hr[i] = (xr[i]-mu)*rs*sg[i] + sb[i];

    // write this head's 8-dim slice of h (static indexing via if-chain)
    {
        float4* hp = (float4*)(h + (size_t)r * DD + hh*HD);
        if (hh == 0) { hp[0]=make_float4(hr[0],hr[1],hr[2],hr[3]);     hp[1]=make_float4(hr[4],hr[5],hr[6],hr[7]); }
        else if (hh == 1) { hp[0]=make_float4(hr[8],hr[9],hr[10],hr[11]);   hp[1]=make_float4(hr[12],hr[13],hr[14],hr[15]); }
        else if (hh == 2) { hp[0]=make_float4(hr[16],hr[17],hr[18],hr[19]); hp[1]=make_float4(hr[20],hr[21],hr[22],hr[23]); }
        else              { hp[0]=make_float4(hr[24],hr[25],hr[26],hr[27]); hp[1]=make_float4(hr[28],hr[29],hr[30],hr[31]); }
    }

    // q,k,v for this head
    const float* wq = sW + hh*256;
    const float* wk = sW + 1024 + hh*256;
    const float* wv = sW + 2048 + hh*256;
    float qa[HD], ka[HD], va[HD];
    #pragma unroll
    for (int kk2 = 0; kk2 < HD; ++kk2) { qa[kk2]=0.f; ka[kk2]=0.f; va[kk2]=0.f; }
    #pragma unroll
    for (int d = 0; d < DD; ++d) {
        float hv = hr[d];
        #pragma unroll
        for (int kk2 = 0; kk2 < HD; ++kk2) {
            qa[kk2] = fmaf(hv, wq[d*HD + kk2], qa[kk2]);
            ka[kk2] = fmaf(hv, wk[d*HD + kk2], ka[kk2]);
            va[kk2] = fmaf(hv, wv[d*HD + kk2], va[kk2]);
        }
    }
    const float SCL = 0.35355339059327373f * 1.4426950408889634f;  // 1/sqrt(8) * log2(e)
    size_t qbase = ((size_t)(bb*HH + hh)*TT + tt) * HD;
    float4* qp = (float4*)(q + qbase);
    qp[0] = make_float4(qa[0]*SCL, qa[1]*SCL, qa[2]*SCL, qa[3]*SCL);
    qp[1] = make_float4(qa[4]*SCL, qa[5]*SCL, qa[6]*SCL, qa[7]*SCL);
    float4* kvp = (float4*)(kv + ((size_t)(bb*HH + hh)*TT + tt) * 16);
    kvp[0] = make_float4(ka[0],ka[1],ka[2],ka[3]);
    kvp[1] = make_float4(ka[4],ka[5],ka[6],ka[7]);
    kvp[2] = make_float4(va[0],va[1],va[2],va[3]);
    kvp[3] = make_float4(va[4],va[5],va[6],va[7]);
}

// ---------------- Kernel 2: flash attention, 4 query rows per wave ----------------
template<bool MASKED>
__device__ __forceinline__ void attn_step(int sc, int lane, int t0, int t3,
    const float* __restrict__ kvb,
    const float (&qr)[4][HD], float (&m)[4], float (&l)[4], float (&acc)[4][HD])
{
    int s  = sc + lane;
    int sl = MASKED ? (s < t3 ? s : t3) : s;
    const float4* kp = (const float4*)(kvb + (size_t)sl * 16);
    float4 k0 = kp[0], k1 = kp[1], v0 = kp[2], v1 = kp[3];
    float kk[HD] = {k0.x,k0.y,k0.z,k0.w,k1.x,k1.y,k1.z,k1.w};
    float vv[HD] = {v0.x,v0.y,v0.z,v0.w,v1.x,v1.y,v1.z,v1.w};

    float dd[4];
    #pragma unroll
    for (int i = 0; i < 4; ++i) {
        float s_ = 0.f;
        #pragma unroll
        for (int j = 0; j < HD; ++j) s_ = fmaf(qr[i][j], kk[j], s_);
        dd[i] = s_ - m[i];
    }
    float dmax = fmaxf(fmaxf(dd[0],dd[1]), fmaxf(dd[2],dd[3]));
    if (__builtin_expect(dmax > 8.f, 0)) {   // rare rescale (defer-max)
        #pragma unroll
        for (int i = 0; i < 4; ++i) {
            float si = dd[i] + m[i];
            float mn = fmaxf(m[i], si);
            float c  = EXP2F(m[i] - mn);
            l[i] *= c;
            #pragma unroll
            for (int j = 0; j < HD; ++j) acc[i][j] *= c;
            dd[i] = si - mn;
            m[i] = mn;
        }
    }
    #pragma unroll
    for (int i = 0; i < 4; ++i) {
        float p = EXP2F(dd[i]);
        if (MASKED) p = (s <= t0 + i) ? p : 0.f;
        l[i] += p;
        #pragma unroll
        for (int j = 0; j < HD; ++j) acc[i][j] = fmaf(p, vv[j], acc[i][j]);
    }
}

__global__ __launch_bounds__(256) void k_attn(
    const float* __restrict__ q, const float* __restrict__ kv, float* __restrict__ o)
{
    int wave = threadIdx.x >> 6;
    int lane = threadIdx.x & 63;
    int grp  = blockIdx.x * 4 + wave;      // 0..16383
    int bh   = grp >> 9;                   // 512 groups of 4 rows per bh
    int t0   = (grp & 511) << 2;
    int t3   = t0 + 3;
    const float* kvb = kv + (size_t)bh * TT * 16;

    float qr[4][HD];
    {
        const float4* qp = (const float4*)(q + ((size_t)bh*TT + t0) * HD);
        #pragma unroll
        for (int i = 0; i < 4; ++i) {
            float4 a = qp[2*i], c = qp[2*i+1];
            qr[i][0]=a.x; qr[i][1]=a.y; qr[i][2]=a.z; qr[i][3]=a.w;
            qr[i][4]=c.x; qr[i][5]=c.y; qr[i][6]=c.z; qr[i][7]=c.w;
        }
    }
    float m[4] = {0.f,0.f,0.f,0.f};
    float l[4] = {0.f,0.f,0.f,0.f};
    float acc[4][HD];
    #pragma unroll
    for (int i = 0; i < 4; ++i)
        #pragma unroll
        for (int j = 0; j < HD; ++j) acc[i][j] = 0.f;

    int nfull = (t0 >= 63) ? ((t0 - 63) >> 6) + 1 : 0;  // iterations with all 64 keys valid for all 4 rows
    int sc = 0;
    for (int it = 0; it < nfull; ++it, sc += 64)
        attn_step<false>(sc, lane, t0, t3, kvb, qr, m, l, acc);
    for (; sc <= t3; sc += 64)
        attn_step<true>(sc, lane, t0, t3, kvb, qr, m, l, acc);

    // wave merge per query row
    #pragma unroll
    for (int i = 0; i < 4; ++i) {
        float M = m[i];
        #pragma unroll
        for (int off = 32; off; off >>= 1) M = fmaxf(M, __shfl_xor(M, off, 64));
        float w = EXP2F(m[i] - M);
        float L = l[i] * w;
        #pragma unroll
        for (int off = 32; off; off >>= 1) L += __shfl_xor(L, off, 64);
        float inv = 1.f / L;
        float ov[HD];
        #pragma unroll
        for (int j = 0; j < HD; ++j) {
            float a = acc[i][j] * w;
            #pragma unroll
            for (int off = 32; off; off >>= 1) a += __shfl_xor(a, off, 64);
            ov[j] = a * inv;
        }
        if (lane == 0) {
            float4* op = (float4*)(o + ((size_t)bh*TT + t0 + i) * HD);
            op[0] = make_float4(ov[0],ov[1],ov[2],ov[3]);
            op[1] = make_float4(ov[4],ov[5],ov[6],ov[7]);
        }
    }
}

// ---------------- Kernel 3: proj + residual + LN2 + FFN (4 threads/row) ----------
__global__ __launch_bounds__(256) void k_proj_ffn(
    const float* __restrict__ h, const float* __restrict__ o,
    const float* __restrict__ Wproj, const float* __restrict__ bproj,
    const float* __restrict__ W1, const float* __restrict__ b1,
    const float* __restrict__ W2, const float* __restrict__ b2,
    const float* __restrict__ g2, const float* __restrict__ bt2,
    float* __restrict__ out)
{
    __shared__ float sWp[DD*DD], sW1T[DD*4*DD], sW2[4*DD*DD];
    __shared__ float sbp[DD], sb1[4*DD], sb2[DD], sg2[DD], sbt2[DD];
    for (int i = threadIdx.x; i < DD*DD; i += 256) sWp[i] = Wproj[i];
    for (int i = threadIdx.x; i < DD*4*DD; i += 256) {
        int j = i >> 5, d = i & 31;
        sW1T[i] = W1[d*4*DD + j];        // transposed: row j holds W1[:,j]
        sW2[i]  = W2[i];                 // row j holds W2[j,:]
    }
    if (threadIdx.x < DD) {
        sbp[threadIdx.x]  = bproj[threadIdx.x];
        sb2[threadIdx.x]  = b2[threadIdx.x];
        sg2[threadIdx.x]  = g2[threadIdx.x];
        sbt2[threadIdx.x] = bt2[threadIdx.x];
    }
    if (threadIdx.x < 4*DD) sb1[threadIdx.x] = b1[threadIdx.x];
    __syncthreads();

    int idx = blockIdx.x * 256 + threadIdx.x;   // 0..65535
    int r   = idx >> 2;
    int sub = idx & 3;
    int bb  = r >> 11, tt = r & 2047;

    float hr[DD];
    {
        const float4* hp = (const float4*)(h + (size_t)r * DD);
        #pragma unroll
        for (int i = 0; i < DD/4; ++i) {
            float4 t4 = hp[i];
            hr[4*i]=t4.x; hr[4*i+1]=t4.y; hr[4*i+2]=t4.z; hr[4*i+3]=t4.w;
        }
    }
    // this thread's head (= sub) slice of o
    float ov8[HD];
    {
        const float4* op4 = (const float4*)(o + ((size_t)(bb*HH + sub)*TT + tt) * HD);
        float4 a = op4[0], c = op4[1];
        ov8[0]=a.x; ov8[1]=a.y; ov8[2]=a.z; ov8[3]=a.w;
        ov8[4]=c.x; ov8[5]=c.y; ov8[6]=c.z; ov8[7]=c.w;
    }
    // partial projection over this thread's 8 input dims (j = sub*8 .. +8)
    float x1[DD];
    #pragma unroll
    for (int d = 0; d < DD; ++d) x1[d] = 0.f;
    #pragma unroll
    for (int jj = 0; jj < 8; ++jj) {
        const float* wrow = &sWp[(sub*8 + jj)*DD];
        float ov = ov8[jj];
        #pragma unroll
        for (int d = 0; d < DD; ++d) x1[d] = fmaf(ov, wrow[d], x1[d]);
    }
    // merge partials across the 4 threads of this row
    #pragma unroll
    for (int d = 0; d < DD; ++d) {
        x1[d] += __shfl_xor(x1[d], 1, 64);
        x1[d] += __shfl_xor(x1[d], 2, 64);
        x1[d] += hr[d] + sbp[d];
    }
    // LN2 (redundant across the 4 threads)
    float mu = 0.f;
    #pragma unroll
    for (int d = 0; d < DD; ++d) mu += x1[d];
    mu *= (1.f/DD);
    float var = 0.f;
    #pragma unroll
    for (int d = 0; d < DD; ++d) { float dl = x1[d]-mu; var += dl*dl; }
    var *= (1.f/DD);
    float rs = rsqrtf(var + LNEPS);
    float h2[DD];
    #pragma unroll
    for (int d = 0; d < DD; ++d) h2[d] = (x1[d]-mu)*rs*sg2[d] + sbt2[d];

    // FFN over this thread's 32 hidden units (j = sub*32 .. +32)
    float outp[DD];
    #pragma unroll
    for (int d = 0; d < DD; ++d) outp[d] = 0.f;
    #pragma unroll
    for (int jj = 0; jj < 32; ++jj) {
        int j = sub*32 + jj;
        const float* w1r = &sW1T[j*DD];
        float a = sb1[j];
        #pragma unroll
        for (int d = 0; d < DD; ++d) a = fmaf(h2[d], w1r[d], a);
        a = fmaxf(a, 0.f);
        const float* w2r = &sW2[j*DD];
        #pragma unroll
        for (int d = 0; d < DD; ++d) outp[d] = fmaf(a, w2r[d], outp[d]);
    }
    #pragma unroll
    for (int d = 0; d < DD; ++d) {
        outp[d] += __shfl_xor(outp[d], 1, 64);
        outp[d] += __shfl_xor(outp[d], 2, 64);
        outp[d] += h2[d] + sb2[d];
    }
    // each thread writes its 8-dim slice (static indexing)
    float4* op = (float4*)(out + (size_t)r * DD + sub*HD);
    if (sub == 0) { op[0]=make_float4(outp[0],outp[1],outp[2],outp[3]);     op[1]=make_float4(outp[4],outp[5],outp[6],outp[7]); }
    else if (sub == 1) { op[0]=make_float4(outp[8],outp[9],outp[10],outp[11]);   op[1]=make_float4(outp[12],outp[13],outp[14],outp[15]); }
    else if (sub == 2) { op[0]=make_float4(outp[16],outp[17],outp[18],outp[19]); op[1]=make_float4(outp[20],outp[21],outp[22],outp[23]); }
    else               { op[0]=make_float4(outp[24],outp[25],outp[26],outp[27]); op[1]=make_float4(outp[28],outp[29],outp[30],outp[31]); }
}

extern "C" void kernel_launch(void* const* d_in, const int* in_sizes, int n_in,
                              void* d_out, int out_size, void* d_ws, size_t ws_size,
                              hipStream_t stream) {
    const float* x     = (const float*)d_in[0];
    const float* Wq    = (const float*)d_in[1];
    const float* Wk    = (const float*)d_in[2];
    const float* Wv    = (const float*)d_in[3];
    const float* Wproj = (const float*)d_in[4];
    const float* bproj = (const float*)d_in[5];
    const float* ln1_g = (const float*)d_in[6];
    const float* ln1_b = (const float*)d_in[7];
    const float* W1    = (const float*)d_in[8];
    const float* b1    = (const float*)d_in[9];
    const float* W2    = (const float*)d_in[10];
    const float* b2    = (const float*)d_in[11];
    const float* ln2_g = (const float*)d_in[12];
    const float* ln2_b = (const float*)d_in[13];
    float* out = (float*)d_out;

    const size_t N = (size_t)NROWS * DD;   // 524288
    float* ws = (float*)d_ws;
    float* h  = ws;                        // N
    float* q  = ws + N;                    // N
    float* kv = ws + 2*N;                  // 2N (k|v interleaved, 16 floats/key)
    float* o  = ws + 4*N;                  // N

    k_ln_qkv <<<256, 256, 0, stream>>>(x, Wq, Wk, Wv, ln1_g, ln1_b, h, q, kv);
    k_attn   <<<4096, 256, 0, stream>>>(q, kv, o);
    k_proj_ffn<<<256, 256, 0, stream>>>(h, o, Wproj, bproj, W1, b1, W2, b2, ln2_g, ln2_b, out);
}

// Round 3
// 192.397 us; speedup vs baseline: 1.4169x; 1.0947x over previous
//
#include <hip/hip_runtime.h>
#include <math.h>

#define BB 8
#define TT 2048
#define DD 32
#define HH 4
#define HD 8
#define NROWS (BB*TT)       // 16384
#define LNEPS 1e-5f

#if __has_builtin(__builtin_amdgcn_exp2f)
#define EXP2F(x) __builtin_amdgcn_exp2f(x)
#else
#define EXP2F(x) __expf(0.6931471805599453f*(x))
#endif

// ---------------- Kernel 1: LN1 + QKV projection (4 threads/row, one head each) ----
__global__ __launch_bounds__(256) void k_ln_qkv(
    const float* __restrict__ x,
    const float* __restrict__ Wq, const float* __restrict__ Wk, const float* __restrict__ Wv,
    const float* __restrict__ g, const float* __restrict__ b,
    float* __restrict__ h, float* __restrict__ q, float* __restrict__ kv)
{
    __shared__ float sW[3*HH*DD*HD];   // Wq | Wk | Wv, each [H][D][HD]
    __shared__ float sg[DD], sb[DD];
    for (int i = threadIdx.x; i < HH*DD*HD; i += 256) {
        sW[i]            = Wq[i];
        sW[1024 + i]     = Wk[i];
        sW[2048 + i]     = Wv[i];
    }
    if (threadIdx.x < DD) { sg[threadIdx.x] = g[threadIdx.x]; sb[threadIdx.x] = b[threadIdx.x]; }
    __syncthreads();

    int idx = blockIdx.x * 256 + threadIdx.x;     // 0..65535
    int r   = idx >> 2;                           // row 0..16383
    int hh  = idx & 3;                            // head
    int bb  = r >> 11, tt = r & 2047;

    float xr[DD];
    {
        const float4* xp = (const float4*)(x + (size_t)r * DD);
        #pragma unroll
        for (int i = 0; i < DD/4; ++i) {
            float4 t4 = xp[i];
            xr[4*i]=t4.x; xr[4*i+1]=t4.y; xr[4*i+2]=t4.z; xr[4*i+3]=t4.w;
        }
    }
    float mu = 0.f;
    #pragma unroll
    for (int i = 0; i < DD; ++i) mu += xr[i];
    mu *= (1.f/DD);
    float var = 0.f;
    #pragma unroll
    for (int i = 0; i < DD; ++i) { float d = xr[i]-mu; var += d*d; }
    var *= (1.f/DD);
    float rs = rsqrtf(var + LNEPS);
    float hr[DD];
    #pragma unroll
    for (int i = 0; i < DD; ++i) hr[i] = (xr[i]-mu)*rs*sg[i] + sb[i];

    // write this head's 8-dim slice of h (static indexing via if-chain)
    {
        float4* hp = (float4*)(h + (size_t)r * DD + hh*HD);
        if (hh == 0) { hp[0]=make_float4(hr[0],hr[1],hr[2],hr[3]);     hp[1]=make_float4(hr[4],hr[5],hr[6],hr[7]); }
        else if (hh == 1) { hp[0]=make_float4(hr[8],hr[9],hr[10],hr[11]);   hp[1]=make_float4(hr[12],hr[13],hr[14],hr[15]); }
        else if (hh == 2) { hp[0]=make_float4(hr[16],hr[17],hr[18],hr[19]); hp[1]=make_float4(hr[20],hr[21],hr[22],hr[23]); }
        else              { hp[0]=make_float4(hr[24],hr[25],hr[26],hr[27]); hp[1]=make_float4(hr[28],hr[29],hr[30],hr[31]); }
    }

    // q,k,v for this head
    const float* wq = sW + hh*256;
    const float* wk = sW + 1024 + hh*256;
    const float* wv = sW + 2048 + hh*256;
    float qa[HD], ka[HD], va[HD];
    #pragma unroll
    for (int kk2 = 0; kk2 < HD; ++kk2) { qa[kk2]=0.f; ka[kk2]=0.f; va[kk2]=0.f; }
    #pragma unroll
    for (int d = 0; d < DD; ++d) {
        float hv = hr[d];
        #pragma unroll
        for (int kk2 = 0; kk2 < HD; ++kk2) {
            qa[kk2] = fmaf(hv, wq[d*HD + kk2], qa[kk2]);
            ka[kk2] = fmaf(hv, wk[d*HD + kk2], ka[kk2]);
            va[kk2] = fmaf(hv, wv[d*HD + kk2], va[kk2]);
        }
    }
    const float SCL = 0.35355339059327373f * 1.4426950408889634f;  // 1/sqrt(8) * log2(e)
    size_t qbase = ((size_t)(bb*HH + hh)*TT + tt) * HD;
    float4* qp = (float4*)(q + qbase);
    qp[0] = make_float4(qa[0]*SCL, qa[1]*SCL, qa[2]*SCL, qa[3]*SCL);
    qp[1] = make_float4(qa[4]*SCL, qa[5]*SCL, qa[6]*SCL, qa[7]*SCL);

    // kv: 16 floats per key; 16-byte chunks [k0,k1,v0,v1] stored XOR-swizzled so that
    // linear LDS staging + swizzled ds_read in k_attn is bank-conflict-free.
    float4* kvp = (float4*)(kv + ((size_t)(bb*HH + hh)*TT + tt) * 16);
    int swz = (tt >> 1) & 3;
    kvp[swz]     = make_float4(ka[0],ka[1],ka[2],ka[3]);
    kvp[swz^1]   = make_float4(ka[4],ka[5],ka[6],ka[7]);
    kvp[swz^2]   = make_float4(va[0],va[1],va[2],va[3]);
    kvp[swz^3]   = make_float4(va[4],va[5],va[6],va[7]);
}

// ---------------- Kernel 2: flash attention, LDS-shared K/V ----------------
// One 64-key sub-chunk: lane l handles key sc+l for this wave's 4 query rows.
template<bool MASKED>
__device__ __forceinline__ void attn_sub(const float* __restrict__ sk, int lane,
    int sc, int t0, const float (&qr)[4][HD],
    float (&m)[4], float (&l)[4], float (&acc)[4][HD])
{
    int sw = (lane >> 1) & 3;                 // matches producer swizzle: key%64 = lane
    const float4* kp = (const float4*)sk + (lane << 2);
    float4 c0 = kp[sw];
    float4 c1 = kp[sw ^ 1];
    float4 c2 = kp[sw ^ 2];
    float4 c3 = kp[sw ^ 3];
    float kk[HD] = {c0.x,c0.y,c0.z,c0.w,c1.x,c1.y,c1.z,c1.w};
    float vv[HD] = {c2.x,c2.y,c2.z,c2.w,c3.x,c3.y,c3.z,c3.w};

    float dd[4];
    #pragma unroll
    for (int i = 0; i < 4; ++i) {
        float s_ = 0.f;
        #pragma unroll
        for (int j = 0; j < HD; ++j) s_ = fmaf(qr[i][j], kk[j], s_);
        dd[i] = s_ - m[i];
        if (MASKED && (sc + lane > t0 + i)) dd[i] = -1e30f;
    }
    float dmax = fmaxf(fmaxf(dd[0],dd[1]), fmaxf(dd[2],dd[3]));
    if (__builtin_expect(dmax > 8.f, 0)) {   // rare rescale (defer-max)
        #pragma unroll
        for (int i = 0; i < 4; ++i) {
            float si = dd[i] + m[i];
            float mn = fmaxf(m[i], si);
            float c  = EXP2F(m[i] - mn);
            l[i] *= c;
            #pragma unroll
            for (int j = 0; j < HD; ++j) acc[i][j] *= c;
            dd[i] = si - mn;
            m[i] = mn;
        }
    }
    #pragma unroll
    for (int i = 0; i < 4; ++i) {
        float p = EXP2F(dd[i]);
        l[i] += p;
        #pragma unroll
        for (int j = 0; j < HD; ++j) acc[i][j] = fmaf(p, vv[j], acc[i][j]);
    }
}

__global__ __launch_bounds__(256) void k_attn(
    const float* __restrict__ q, const float* __restrict__ kv, float* __restrict__ o)
{
    __shared__ float skv[2][2048];            // 2 x (128 keys x 16 floats) = 16 KB
    int tid  = threadIdx.x;
    int wave = tid >> 6;
    int lane = tid & 63;
    int bh   = blockIdx.x >> 7;                       // 128 blocks per (b,h)
    int tb   = (127 - (int)(blockIdx.x & 127)) << 4;  // heavy blocks first
    int t0   = tb + (wave << 2);
    int t3   = t0 + 3;
    int tmax = tb + 15;
    const float* kvb = kv + (size_t)bh * TT * 16;

    float qr[4][HD];
    {
        const float4* qp = (const float4*)(q + ((size_t)bh*TT + t0) * HD);
        #pragma unroll
        for (int i = 0; i < 4; ++i) {
            float4 a = qp[2*i], c = qp[2*i+1];
            qr[i][0]=a.x; qr[i][1]=a.y; qr[i][2]=a.z; qr[i][3]=a.w;
            qr[i][4]=c.x; qr[i][5]=c.y; qr[i][6]=c.z; qr[i][7]=c.w;
        }
    }
    float m[4] = {0.f,0.f,0.f,0.f};
    float l[4] = {0.f,0.f,0.f,0.f};
    float acc[4][HD];
    #pragma unroll
    for (int i = 0; i < 4; ++i)
        #pragma unroll
        for (int j = 0; j < HD; ++j) acc[i][j] = 0.f;

    int nit = (tmax >> 7) + 1;                 // 128-key chunks

    // prologue: stage chunk 0
    {
        float4 p0 = *(const float4*)(kvb + (size_t)tid*4);
        float4 p1 = *(const float4*)(kvb + 1024 + (size_t)tid*4);
        ((float4*)&skv[0][0])[tid]       = p0;
        ((float4*)&skv[0][0])[tid + 256] = p1;
    }
    __syncthreads();

    int buf = 0;
    for (int it = 0; it < nit; ++it) {
        int sc = it << 7;
        float4 p0, p1;
        bool stage = (it + 1 < nit);
        if (stage) {                                   // issue next-chunk loads EARLY
            const float* gsrc = kvb + (size_t)(it+1) * 2048;
            p0 = *(const float4*)(gsrc + (size_t)tid*4);
            p1 = *(const float4*)(gsrc + 1024 + (size_t)tid*4);
        }
        // compute current chunk (covers the load latency)
        if (sc <= t3) {
            if (sc + 63 <= t0)       attn_sub<false>(&skv[buf][0],    lane, sc,    t0, qr, m, l, acc);
            else                     attn_sub<true >(&skv[buf][0],    lane, sc,    t0, qr, m, l, acc);
            int sc1 = sc + 64;
            if (sc1 <= t3) {
                if (sc1 + 63 <= t0)  attn_sub<false>(&skv[buf][1024], lane, sc1,   t0, qr, m, l, acc);
                else                 attn_sub<true >(&skv[buf][1024], lane, sc1,   t0, qr, m, l, acc);
            }
        }
        if (stage) {                                   // write LATE (vmcnt drained under compute)
            ((float4*)&skv[buf^1][0])[tid]       = p0;
            ((float4*)&skv[buf^1][0])[tid + 256] = p1;
        }
        __syncthreads();
        buf ^= 1;
    }

    // wave merge per query row
    #pragma unroll
    for (int i = 0; i < 4; ++i) {
        float M = m[i];
        #pragma unroll
        for (int off = 32; off; off >>= 1) M = fmaxf(M, __shfl_xor(M, off, 64));
        float w = EXP2F(m[i] - M);
        float L = l[i] * w;
        #pragma unroll
        for (int off = 32; off; off >>= 1) L += __shfl_xor(L, off, 64);
        float inv = 1.f / L;
        float ov[HD];
        #pragma unroll
        for (int j = 0; j < HD; ++j) {
            float a = acc[i][j] * w;
            #pragma unroll
            for (int off = 32; off; off >>= 1) a += __shfl_xor(a, off, 64);
            ov[j] = a * inv;
        }
        if (lane == 0) {
            float4* op = (float4*)(o + ((size_t)bh*TT + t0 + i) * HD);
            op[0] = make_float4(ov[0],ov[1],ov[2],ov[3]);
            op[1] = make_float4(ov[4],ov[5],ov[6],ov[7]);
        }
    }
}

// ---------------- Kernel 3: proj + residual + LN2 + FFN (4 threads/row) ----------
__global__ __launch_bounds__(256) void k_proj_ffn(
    const float* __restrict__ h, const float* __restrict__ o,
    const float* __restrict__ Wproj, const float* __restrict__ bproj,
    const float* __restrict__ W1, const float* __restrict__ b1,
    const float* __restrict__ W2, const float* __restrict__ b2,
    const float* __restrict__ g2, const float* __restrict__ bt2,
    float* __restrict__ out)
{
    __shared__ float sWp[DD*DD], sW1T[DD*4*DD], sW2[4*DD*DD];
    __shared__ float sbp[DD], sb1[4*DD], sb2[DD], sg2[DD], sbt2[DD];
    for (int i = threadIdx.x; i < DD*DD; i += 256) sWp[i] = Wproj[i];
    for (int i = threadIdx.x; i < DD*4*DD; i += 256) {
        int j = i >> 5, d = i & 31;
        sW1T[i] = W1[d*4*DD + j];        // transposed: row j holds W1[:,j]
        sW2[i]  = W2[i];                 // row j holds W2[j,:]
    }
    if (threadIdx.x < DD) {
        sbp[threadIdx.x]  = bproj[threadIdx.x];
        sb2[threadIdx.x]  = b2[threadIdx.x];
        sg2[threadIdx.x]  = g2[threadIdx.x];
        sbt2[threadIdx.x] = bt2[threadIdx.x];
    }
    if (threadIdx.x < 4*DD) sb1[threadIdx.x] = b1[threadIdx.x];
    __syncthreads();

    int idx = blockIdx.x * 256 + threadIdx.x;   // 0..65535
    int r   = idx >> 2;
    int sub = idx & 3;
    int bb  = r >> 11, tt = r & 2047;

    float hr[DD];
    {
        const float4* hp = (const float4*)(h + (size_t)r * DD);
        #pragma unroll
        for (int i = 0; i < DD/4; ++i) {
            float4 t4 = hp[i];
            hr[4*i]=t4.x; hr[4*i+1]=t4.y; hr[4*i+2]=t4.z; hr[4*i+3]=t4.w;
        }
    }
    // this thread's head (= sub) slice of o
    float ov8[HD];
    {
        const float4* op4 = (const float4*)(o + ((size_t)(bb*HH + sub)*TT + tt) * HD);
        float4 a = op4[0], c = op4[1];
        ov8[0]=a.x; ov8[1]=a.y; ov8[2]=a.z; ov8[3]=a.w;
        ov8[4]=c.x; ov8[5]=c.y; ov8[6]=c.z; ov8[7]=c.w;
    }
    // partial projection over this thread's 8 input dims (j = sub*8 .. +8)
    float x1[DD];
    #pragma unroll
    for (int d = 0; d < DD; ++d) x1[d] = 0.f;
    #pragma unroll
    for (int jj = 0; jj < 8; ++jj) {
        const float* wrow = &sWp[(sub*8 + jj)*DD];
        float ov = ov8[jj];
        #pragma unroll
        for (int d = 0; d < DD; ++d) x1[d] = fmaf(ov, wrow[d], x1[d]);
    }
    // merge partials across the 4 threads of this row
    #pragma unroll
    for (int d = 0; d < DD; ++d) {
        x1[d] += __shfl_xor(x1[d], 1, 64);
        x1[d] += __shfl_xor(x1[d], 2, 64);
        x1[d] += hr[d] + sbp[d];
    }
    // LN2 (redundant across the 4 threads)
    float mu = 0.f;
    #pragma unroll
    for (int d = 0; d < DD; ++d) mu += x1[d];
    mu *= (1.f/DD);
    float var = 0.f;
    #pragma unroll
    for (int d = 0; d < DD; ++d) { float dl = x1[d]-mu; var += dl*dl; }
    var *= (1.f/DD);
    float rs = rsqrtf(var + LNEPS);
    float h2[DD];
    #pragma unroll
    for (int d = 0; d < DD; ++d) h2[d] = (x1[d]-mu)*rs*sg2[d] + sbt2[d];

    // FFN over this thread's 32 hidden units (j = sub*32 .. +32)
    float outp[DD];
    #pragma unroll
    for (int d = 0; d < DD; ++d) outp[d] = 0.f;
    #pragma unroll
    for (int jj = 0; jj < 32; ++jj) {
        int j = sub*32 + jj;
        const float* w1r = &sW1T[j*DD];
        float a = sb1[j];
        #pragma unroll
        for (int d = 0; d < DD; ++d) a = fmaf(h2[d], w1r[d], a);
        a = fmaxf(a, 0.f);
        const float* w2r = &sW2[j*DD];
        #pragma unroll
        for (int d = 0; d < DD; ++d) outp[d] = fmaf(a, w2r[d], outp[d]);
    }
    #pragma unroll
    for (int d = 0; d < DD; ++d) {
        outp[d] += __shfl_xor(outp[d], 1, 64);
        outp[d] += __shfl_xor(outp[d], 2, 64);
        outp[d] += h2[d] + sb2[d];
    }
    // each thread writes its 8-dim slice (static indexing)
    float4* op = (float4*)(out + (size_t)r * DD + sub*HD);
    if (sub == 0) { op[0]=make_float4(outp[0],outp[1],outp[2],outp[3]);     op[1]=make_float4(outp[4],outp[5],outp[6],outp[7]); }
    else if (sub == 1) { op[0]=make_float4(outp[8],outp[9],outp[10],outp[11]);   op[1]=make_float4(outp[12],outp[13],outp[14],outp[15]); }
    else if (sub == 2) { op[0]=make_float4(outp[16],outp[17],outp[18],outp[19]); op[1]=make_float4(outp[20],outp[21],outp[22],outp[23]); }
    else               { op[0]=make_float4(outp[24],outp[25],outp[26],outp[27]); op[1]=make_float4(outp[28],outp[29],outp[30],outp[31]); }
}

extern "C" void kernel_launch(void* const* d_in, const int* in_sizes, int n_in,
                              void* d_out, int out_size, void* d_ws, size_t ws_size,
                              hipStream_t stream) {
    const float* x     = (const float*)d_in[0];
    const float* Wq    = (const float*)d_in[1];
    const float* Wk    = (const float*)d_in[2];
    const float* Wv    = (const float*)d_in[3];
    const float* Wproj = (const float*)d_in[4];
    const float* bproj = (const float*)d_in[5];
    const float* ln1_g = (const float*)d_in[6];
    const float* ln1_b = (const float*)d_in[7];
    const float* W1    = (const float*)d_in[8];
    const float* b1    = (const float*)d_in[9];
    const float* W2    = (const float*)d_in[10];
    const float* b2    = (const float*)d_in[11];
    const float* ln2_g = (const float*)d_in[12];
    const float* ln2_b = (const float*)d_in[13];
    float* out = (float*)d_out;

    const size_t N = (size_t)NROWS * DD;   // 524288
    float* ws = (float*)d_ws;
    float* h  = ws;                        // N
    float* q  = ws + N;                    // N
    float* kv = ws + 2*N;                  // 2N (k|v interleaved+swizzled, 16 floats/key)
    float* o  = ws + 4*N;                  // N

    k_ln_qkv <<<256, 256, 0, stream>>>(x, Wq, Wk, Wv, ln1_g, ln1_b, h, q, kv);
    k_attn   <<<4096, 256, 0, stream>>>(q, kv, o);
    k_proj_ffn<<<256, 256, 0, stream>>>(h, o, Wproj, bproj, W1, b1, W2, b2, ln2_g, ln2_b, out);
}

// Round 5
// 174.052 us; speedup vs baseline: 1.5663x; 1.1054x over previous
//
#include <hip/hip_runtime.h>
#include <math.h>

#define BB 8
#define TT 2048
#define DD 32
#define HH 4
#define HD 8
#define NROWS (BB*TT)       // 16384 (B*T); attention rows = B*H*T = 65536
#define LNEPS 1e-5f

#if __has_builtin(__builtin_amdgcn_exp2f)
#define EXP2F(x) __builtin_amdgcn_exp2f(x)
#else
#define EXP2F(x) __expf(0.6931471805599453f*(x))
#endif

typedef _Float16 h2 __attribute__((ext_vector_type(2)));
struct KH { h2 a, b, c, d; };               // 16B: 8 halves
union F4H { float4 f; KH k; };

static __device__ __forceinline__ h2 pkrtz(float a, float b) {
    return __builtin_bit_cast(h2, __builtin_amdgcn_cvt_pkrtz(a, b));
}

#if __has_builtin(__builtin_amdgcn_fdot2)
#define DOT2(a,b,c) __builtin_amdgcn_fdot2((a),(b),(c),false)
#else
#define DOT2(a,b,c) fmaf((float)(a)[1],(float)(b)[1], fmaf((float)(a)[0],(float)(b)[0],(c)))
#endif

// ---------------- Kernel 1: LN1 + QKV projection (8 threads/row) ----------------
// sub = idx&7: hh = sub&3 (head), dh = sub>>2 (which 16 input dims to reduce)
__global__ __launch_bounds__(256) void k_ln_qkv(
    const float* __restrict__ x,
    const float* __restrict__ Wq, const float* __restrict__ Wk, const float* __restrict__ Wv,
    const float* __restrict__ g, const float* __restrict__ b,
    float* __restrict__ h, float* __restrict__ qh,
    float* __restrict__ Kh, float* __restrict__ V0, float* __restrict__ V1)
{
    // per-head stride 264 (=256+8) so heads land in distinct bank groups
    __shared__ float sW[3*HH*264];
    __shared__ float sg[DD], sb[DD];
    for (int i = threadIdx.x; i < HH*DD*HD; i += 256) {
        int hd_ = i >> 8, off = i & 255;
        sW[hd_*264 + off]              = Wq[i];
        sW[(4+hd_)*264 + off]          = Wk[i];
        sW[(8+hd_)*264 + off]          = Wv[i];
    }
    if (threadIdx.x < DD) { sg[threadIdx.x] = g[threadIdx.x]; sb[threadIdx.x] = b[threadIdx.x]; }
    __syncthreads();

    int idx = blockIdx.x * 256 + threadIdx.x;     // 0..131071
    int r   = idx >> 3;                           // row 0..16383
    int sub = idx & 7;
    int hh  = sub & 3;
    int dh  = sub >> 2;                           // 0/1 -> dims dh*16..+15
    int bb  = r >> 11, tt = r & 2047;

    float xr[16];
    {
        const float4* xp = (const float4*)(x + (size_t)r * DD + dh*16);
        float4 t0 = xp[0], t1 = xp[1], t2 = xp[2], t3 = xp[3];
        xr[0]=t0.x; xr[1]=t0.y; xr[2]=t0.z; xr[3]=t0.w;
        xr[4]=t1.x; xr[5]=t1.y; xr[6]=t1.z; xr[7]=t1.w;
        xr[8]=t2.x; xr[9]=t2.y; xr[10]=t2.z; xr[11]=t2.w;
        xr[12]=t3.x; xr[13]=t3.y; xr[14]=t3.z; xr[15]=t3.w;
    }
    float s1 = 0.f;
    #pragma unroll
    for (int i = 0; i < 16; ++i) s1 += xr[i];
    s1 += __shfl_xor(s1, 4, 64);
    float mu = s1 * (1.f/DD);
    float sq = 0.f;
    #pragma unroll
    for (int i = 0; i < 16; ++i) { float d = xr[i]-mu; sq += d*d; }
    sq += __shfl_xor(sq, 4, 64);
    float rs = rsqrtf(sq * (1.f/DD) + LNEPS);

    float hr[16];
    #pragma unroll
    for (int i = 0; i < 16; ++i) hr[i] = (xr[i]-mu)*rs*sg[dh*16+i] + sb[dh*16+i];

    // write own 16-dim slice of h
    {
        float4* hp = (float4*)(h + (size_t)r * DD + dh*16);
        hp[0]=make_float4(hr[0],hr[1],hr[2],hr[3]);
        hp[1]=make_float4(hr[4],hr[5],hr[6],hr[7]);
        hp[2]=make_float4(hr[8],hr[9],hr[10],hr[11]);
        hp[3]=make_float4(hr[12],hr[13],hr[14],hr[15]);
    }

    // partial q,k,v over own 16 input dims
    const float* wq = sW + hh*264 + dh*128;
    const float* wk = sW + (4+hh)*264 + dh*128;
    const float* wv = sW + (8+hh)*264 + dh*128;
    float qa[HD], ka[HD], va[HD];
    #pragma unroll
    for (int k2 = 0; k2 < HD; ++k2) { qa[k2]=0.f; ka[k2]=0.f; va[k2]=0.f; }
    #pragma unroll
    for (int d = 0; d < 16; ++d) {
        float hv = hr[d];
        const float4* wq4 = (const float4*)(wq + d*8);
        const float4* wk4 = (const float4*)(wk + d*8);
        const float4* wv4 = (const float4*)(wv + d*8);
        float4 a0 = wq4[0], a1 = wq4[1];
        float4 b0 = wk4[0], b1 = wk4[1];
        float4 c0 = wv4[0], c1 = wv4[1];
        qa[0]=fmaf(hv,a0.x,qa[0]); qa[1]=fmaf(hv,a0.y,qa[1]); qa[2]=fmaf(hv,a0.z,qa[2]); qa[3]=fmaf(hv,a0.w,qa[3]);
        qa[4]=fmaf(hv,a1.x,qa[4]); qa[5]=fmaf(hv,a1.y,qa[5]); qa[6]=fmaf(hv,a1.z,qa[6]); qa[7]=fmaf(hv,a1.w,qa[7]);
        ka[0]=fmaf(hv,b0.x,ka[0]); ka[1]=fmaf(hv,b0.y,ka[1]); ka[2]=fmaf(hv,b0.z,ka[2]); ka[3]=fmaf(hv,b0.w,ka[3]);
        ka[4]=fmaf(hv,b1.x,ka[4]); ka[5]=fmaf(hv,b1.y,ka[5]); ka[6]=fmaf(hv,b1.z,ka[6]); ka[7]=fmaf(hv,b1.w,ka[7]);
        va[0]=fmaf(hv,c0.x,va[0]); va[1]=fmaf(hv,c0.y,va[1]); va[2]=fmaf(hv,c0.z,va[2]); va[3]=fmaf(hv,c0.w,va[3]);
        va[4]=fmaf(hv,c1.x,va[4]); va[5]=fmaf(hv,c1.y,va[5]); va[6]=fmaf(hv,c1.z,va[6]); va[7]=fmaf(hv,c1.w,va[7]);
    }
    // merge the two dh-halves
    #pragma unroll
    for (int k2 = 0; k2 < HD; ++k2) {
        qa[k2] += __shfl_xor(qa[k2], 4, 64);
        ka[k2] += __shfl_xor(ka[k2], 4, 64);
        va[k2] += __shfl_xor(va[k2], 4, 64);
    }

    const float SCL = 0.35355339059327373f * 1.4426950408889634f;  // 1/sqrt(8)*log2e
    size_t key = (size_t)(bb*HH + hh)*TT + tt;
    if (dh == 0) {
        F4H u;
        u.k.a = pkrtz(qa[0]*SCL, qa[1]*SCL);
        u.k.b = pkrtz(qa[2]*SCL, qa[3]*SCL);
        u.k.c = pkrtz(qa[4]*SCL, qa[5]*SCL);
        u.k.d = pkrtz(qa[6]*SCL, qa[7]*SCL);
        *(float4*)(qh + key*4) = u.f;
        *(float4*)(V0 + key*4) = make_float4(va[0],va[1],va[2],va[3]);
    } else {
        F4H u;
        u.k.a = pkrtz(ka[0], ka[1]);
        u.k.b = pkrtz(ka[2], ka[3]);
        u.k.c = pkrtz(ka[4], ka[5]);
        u.k.d = pkrtz(ka[6], ka[7]);
        *(float4*)(Kh + key*4) = u.f;
        *(float4*)(V1 + key*4) = make_float4(va[4],va[5],va[6],va[7]);
    }
}

// ---------------- Kernel 2: flash attention (f16 dot2 QK, f32 PV) ----------------
template<bool MASKED>
__device__ __forceinline__ void attn_sub(
    const float* __restrict__ sK, const float* __restrict__ sV0, const float* __restrict__ sV1,
    int kl0, int lane, int sc, int t0, const KH (&qk)[4],
    float (&m)[4], float (&l)[4], float (&acc)[4][HD])
{
    int kl = kl0 + lane;                       // local key in chunk
    F4H ku; ku.f = *(const float4*)(sK + (size_t)kl*4);
    KH kh = ku.k;
    float4 v0 = *(const float4*)(sV0 + (size_t)kl*4);
    float4 v1 = *(const float4*)(sV1 + (size_t)kl*4);

    int s = sc + lane;
    float dd[4];
    #pragma unroll
    for (int i = 0; i < 4; ++i) {
        float d = -m[i];
        d = DOT2(qk[i].a, kh.a, d);
        d = DOT2(qk[i].b, kh.b, d);
        d = DOT2(qk[i].c, kh.c, d);
        d = DOT2(qk[i].d, kh.d, d);
        if (MASKED && (s > t0 + i)) d = -1e30f;
        dd[i] = d;
    }
    float dmax = fmaxf(fmaxf(dd[0],dd[1]), fmaxf(dd[2],dd[3]));
    if (__builtin_expect(dmax > 8.f, 0)) {     // defer-max: rare rescale
        #pragma unroll
        for (int i = 0; i < 4; ++i) {
            float si = dd[i] + m[i];
            float mn = fmaxf(m[i], si);
            float c  = EXP2F(m[i] - mn);
            l[i] *= c;
            #pragma unroll
            for (int j = 0; j < HD; ++j) acc[i][j] *= c;
            dd[i] = si - mn;
            m[i] = mn;
        }
    }
    float vv[HD] = {v0.x,v0.y,v0.z,v0.w,v1.x,v1.y,v1.z,v1.w};
    #pragma unroll
    for (int i = 0; i < 4; ++i) {
        float p = EXP2F(dd[i]);
        l[i] += p;
        #pragma unroll
        for (int j = 0; j < HD; ++j) acc[i][j] = fmaf(p, vv[j], acc[i][j]);
    }
}

__global__ __launch_bounds__(256) void k_attn(
    const float* __restrict__ qh, const float* __restrict__ Kh,
    const float* __restrict__ V0, const float* __restrict__ V1,
    float* __restrict__ o)
{
    __shared__ float sK[2][1024], sV0[2][1024], sV1[2][1024];  // 256 keys/chunk, dbuf = 24KB
    int tid  = threadIdx.x;
    int wave = tid >> 6;
    int lane = tid & 63;
    int bh   = blockIdx.x >> 7;                       // 128 blocks per (b,h)
    int tb   = (127 - (int)(blockIdx.x & 127)) << 4;  // heavy blocks first
    int t0   = tb + (wave << 2);
    int t3   = t0 + 3;
    int tmax = tb + 15;

    const float* Kb  = Kh + (size_t)bh * TT * 4;
    const float* V0b = V0 + (size_t)bh * TT * 4;
    const float* V1b = V1 + (size_t)bh * TT * 4;

    KH qk[4];
    {
        const float4* qp = (const float4*)(qh + ((size_t)bh*TT + t0) * 4);
        #pragma unroll
        for (int i = 0; i < 4; ++i) { F4H u; u.f = qp[i]; qk[i] = u.k; }
    }
    float m[4] = {0.f,0.f,0.f,0.f};
    float l[4] = {0.f,0.f,0.f,0.f};
    float acc[4][HD];
    #pragma unroll
    for (int i = 0; i < 4; ++i)
        #pragma unroll
        for (int j = 0; j < HD; ++j) acc[i][j] = 0.f;

    int nit = (tmax >> 8) + 1;                 // 256-key chunks

    // prologue: stage chunk 0 (thread tid -> key tid of chunk)
    {
        float4 pk = *(const float4*)(Kb  + (size_t)tid*4);
        float4 p0 = *(const float4*)(V0b + (size_t)tid*4);
        float4 p1 = *(const float4*)(V1b + (size_t)tid*4);
        ((float4*)&sK [0][0])[tid] = pk;
        ((float4*)&sV0[0][0])[tid] = p0;
        ((float4*)&sV1[0][0])[tid] = p1;
    }
    __syncthreads();

    int buf = 0;
    for (int it = 0; it < nit; ++it) {
        float4 pk, p0, p1;
        bool stage = (it + 1 < nit);
        if (stage) {                                   // issue next-chunk loads EARLY
            size_t g = (size_t)(it+1) * 1024 + tid*4;
            pk = *(const float4*)(Kb  + g);
            p0 = *(const float4*)(V0b + g);
            p1 = *(const float4*)(V1b + g);
        }
        // compute current chunk: 4 sub-blocks of 64 keys
        #pragma unroll
        for (int s4 = 0; s4 < 4; ++s4) {
            int sc = (it << 8) + (s4 << 6);
            if (sc <= t3) {
                if (sc + 63 <= t0) attn_sub<false>(&sK[buf][0], &sV0[buf][0], &sV1[buf][0], s4<<6, lane, sc, t0, qk, m, l, acc);
                else               attn_sub<true >(&sK[buf][0], &sV0[buf][0], &sV1[buf][0], s4<<6, lane, sc, t0, qk, m, l, acc);
            }
        }
        if (stage) {                                   // write LATE
            ((float4*)&sK [buf^1][0])[tid] = pk;
            ((float4*)&sV0[buf^1][0])[tid] = p0;
            ((float4*)&sV1[buf^1][0])[tid] = p1;
        }
        __syncthreads();
        buf ^= 1;
    }

    // wave merge per query row
    #pragma unroll
    for (int i = 0; i < 4; ++i) {
        float M = m[i];
        #pragma unroll
        for (int off = 32; off; off >>= 1) M = fmaxf(M, __shfl_xor(M, off, 64));
        float w = EXP2F(m[i] - M);
        float L = l[i] * w;
        #pragma unroll
        for (int off = 32; off; off >>= 1) L += __shfl_xor(L, off, 64);
        float inv = 1.f / L;
        float ov[HD];
        #pragma unroll
        for (int j = 0; j < HD; ++j) {
            float a = acc[i][j] * w;
            #pragma unroll
            for (int off = 32; off; off >>= 1) a += __shfl_xor(a, off, 64);
            ov[j] = a * inv;
        }
        if (lane == 0) {
            float4* op = (float4*)(o + ((size_t)bh*TT + t0 + i) * HD);
            op[0] = make_float4(ov[0],ov[1],ov[2],ov[3]);
            op[1] = make_float4(ov[4],ov[5],ov[6],ov[7]);
        }
    }
}

// ---------------- Kernel 3: proj + residual + LN2 + FFN (8 threads/row) ----------
// thread sub owns input dims / hidden units j with j % 8 == sub (conflict-free with
// LDS row stride 36 floats: bank group = 9j mod 8 = j mod 8)
__global__ __launch_bounds__(256) void k_proj_ffn(
    const float* __restrict__ h, const float* __restrict__ o,
    const float* __restrict__ Wproj, const float* __restrict__ bproj,
    const float* __restrict__ W1, const float* __restrict__ b1,
    const float* __restrict__ W2, const float* __restrict__ b2,
    const float* __restrict__ g2, const float* __restrict__ bt2,
    float* __restrict__ out)
{
    __shared__ float sWp[DD*36], sW1T[4*DD*36], sW2[4*DD*36];
    __shared__ float sbp[DD], sb1[4*DD], sb2[DD], sg2[DD], sbt2[DD];
    for (int i = threadIdx.x; i < DD*DD; i += 256)      sWp [(i>>5)*36 + (i&31)] = Wproj[i];
    for (int i = threadIdx.x; i < DD*4*DD; i += 256) {
        sW1T[(i&127)*36 + (i>>7)] = W1[i];   // W1[d][j] -> row j, col d (coalesced global)
        sW2 [(i>>5)*36 + (i&31)]  = W2[i];   // W2[j][d] -> row j, col d
    }
    if (threadIdx.x < DD) {
        sbp[threadIdx.x]  = bproj[threadIdx.x];
        sb2[threadIdx.x]  = b2[threadIdx.x];
        sg2[threadIdx.x]  = g2[threadIdx.x];
        sbt2[threadIdx.x] = bt2[threadIdx.x];
    }
    if (threadIdx.x < 4*DD) sb1[threadIdx.x] = b1[threadIdx.x];
    __syncthreads();

    int idx = blockIdx.x * 256 + threadIdx.x;   // 0..131071
    int r   = idx >> 3;
    int sub = idx & 7;
    int bb  = r >> 11, tt = r & 2047;

    // o components j = sub + 8m  (head m, component sub)
    float o4[4];
    #pragma unroll
    for (int mm = 0; mm < 4; ++mm)
        o4[mm] = o[((size_t)(bb*HH + mm)*TT + tt) * HD + sub];

    // proj partials over this thread's 4 input dims
    float x1[DD];
    #pragma unroll
    for (int d = 0; d < DD; ++d) x1[d] = 0.f;
    #pragma unroll
    for (int mm = 0; mm < 4; ++mm) {
        const float4* wr = (const float4*)&sWp[(sub + 8*mm)*36];
        float ov = o4[mm];
        #pragma unroll
        for (int dc = 0; dc < 8; ++dc) {
            float4 w4 = wr[dc];
            x1[4*dc]   = fmaf(ov, w4.x, x1[4*dc]);
            x1[4*dc+1] = fmaf(ov, w4.y, x1[4*dc+1]);
            x1[4*dc+2] = fmaf(ov, w4.z, x1[4*dc+2]);
            x1[4*dc+3] = fmaf(ov, w4.w, x1[4*dc+3]);
        }
    }
    // allreduce x1 across the 8 threads of this row (xor 1,2,4)
    #pragma unroll
    for (int d = 0; d < DD; ++d) {
        x1[d] += __shfl_xor(x1[d], 1, 64);
        x1[d] += __shfl_xor(x1[d], 2, 64);
        x1[d] += __shfl_xor(x1[d], 4, 64);
    }
    // + residual h + bproj
    {
        const float4* hp = (const float4*)(h + (size_t)r * DD);
        #pragma unroll
        for (int dc = 0; dc < 8; ++dc) {
            float4 h4 = hp[dc];
            x1[4*dc]   += h4.x + sbp[4*dc];
            x1[4*dc+1] += h4.y + sbp[4*dc+1];
            x1[4*dc+2] += h4.z + sbp[4*dc+2];
            x1[4*dc+3] += h4.w + sbp[4*dc+3];
        }
    }
    // LN2 (redundant across 8 threads)
    float mu = 0.f;
    #pragma unroll
    for (int d = 0; d < DD; ++d) mu += x1[d];
    mu *= (1.f/DD);
    float var = 0.f;
    #pragma unroll
    for (int d = 0; d < DD; ++d) { float dl = x1[d]-mu; var += dl*dl; }
    var *= (1.f/DD);
    float rs = rsqrtf(var + LNEPS);
    float h2v[DD];
    #pragma unroll
    for (int d = 0; d < DD; ++d) h2v[d] = (x1[d]-mu)*rs*sg2[d] + sbt2[d];

    // FFN: this thread's 16 hidden units j = sub + 8m
    float outp[DD];
    #pragma unroll
    for (int d = 0; d < DD; ++d) outp[d] = 0.f;
    #pragma unroll
    for (int mm = 0; mm < 16; ++mm) {
        int j = sub + 8*mm;
        const float4* w1r = (const float4*)&sW1T[j*36];
        float a = sb1[j];
        #pragma unroll
        for (int dc = 0; dc < 8; ++dc) {
            float4 w4 = w1r[dc];
            a = fmaf(h2v[4*dc], w4.x, a);
            a = fmaf(h2v[4*dc+1], w4.y, a);
            a = fmaf(h2v[4*dc+2], w4.z, a);
            a = fmaf(h2v[4*dc+3], w4.w, a);
        }
        a = fmaxf(a, 0.f);
        const float4* w2r = (const float4*)&sW2[j*36];
        #pragma unroll
        for (int dc = 0; dc < 8; ++dc) {
            float4 w4 = w2r[dc];
            outp[4*dc]   = fmaf(a, w4.x, outp[4*dc]);
            outp[4*dc+1] = fmaf(a, w4.y, outp[4*dc+1]);
            outp[4*dc+2] = fmaf(a, w4.z, outp[4*dc+2]);
            outp[4*dc+3] = fmaf(a, w4.w, outp[4*dc+3]);
        }
    }
    // residual added exactly once (sub==0 lane), then reduce-scatter
    if (sub == 0) {
        #pragma unroll
        for (int d = 0; d < DD; ++d) outp[d] += h2v[d] + sb2[d];
    }
    // reduce-scatter: 3 levels (xor 4, 2, 1); lane sub ends owning dims 4*sub..+3
    float t1[16];
    #pragma unroll
    for (int i = 0; i < 16; ++i) {
        bool hi = (sub & 4) != 0;
        float send = hi ? outp[i] : outp[i+16];
        float recv = __shfl_xor(send, 4, 64);
        t1[i] = (hi ? outp[i+16] : outp[i]) + recv;
    }
    float t2[8];
    #pragma unroll
    for (int i = 0; i < 8; ++i) {
        bool hi = (sub & 2) != 0;
        float send = hi ? t1[i] : t1[i+8];
        float recv = __shfl_xor(send, 2, 64);
        t2[i] = (hi ? t1[i+8] : t1[i]) + recv;
    }
    float w0[4];
    #pragma unroll
    for (int i = 0; i < 4; ++i) {
        bool hi = (sub & 1) != 0;
        float send = hi ? t2[i] : t2[i+4];
        float recv = __shfl_xor(send, 1, 64);
        w0[i] = (hi ? t2[i+4] : t2[i]) + recv;
    }
    *(float4*)(out + (size_t)r * DD + sub*4) = make_float4(w0[0], w0[1], w0[2], w0[3]);
}

extern "C" void kernel_launch(void* const* d_in, const int* in_sizes, int n_in,
                              void* d_out, int out_size, void* d_ws, size_t ws_size,
                              hipStream_t stream) {
    const float* x     = (const float*)d_in[0];
    const float* Wq    = (const float*)d_in[1];
    const float* Wk    = (const float*)d_in[2];
    const float* Wv    = (const float*)d_in[3];
    const float* Wproj = (const float*)d_in[4];
    const float* bproj = (const float*)d_in[5];
    const float* ln1_g = (const float*)d_in[6];
    const float* ln1_b = (const float*)d_in[7];
    const float* W1    = (const float*)d_in[8];
    const float* b1    = (const float*)d_in[9];
    const float* W2    = (const float*)d_in[10];
    const float* b2    = (const float*)d_in[11];
    const float* ln2_g = (const float*)d_in[12];
    const float* ln2_b = (const float*)d_in[13];
    float* out = (float*)d_out;

    const size_t N = (size_t)NROWS * DD;   // 524288
    const size_t K = (size_t)BB*HH*TT*4;   // 262144 (4 floats per attn row)
    float* ws = (float*)d_ws;
    float* h  = ws;                        // N
    float* qh = ws + N;                    // K (f16x8 packed per row)
    float* Kh = ws + N + K;                // K (f16x8 packed per key)
    float* V0 = ws + N + 2*K;              // K
    float* V1 = ws + N + 3*K;              // K
    float* o  = ws + N + 4*K;              // N

    k_ln_qkv  <<<512, 256, 0, stream>>>(x, Wq, Wk, Wv, ln1_g, ln1_b, h, qh, Kh, V0, V1);
    k_attn    <<<4096, 256, 0, stream>>>(qh, Kh, V0, V1, o);
    k_proj_ffn<<<512, 256, 0, stream>>>(h, o, Wproj, bproj, W1, b1, W2, b2, ln2_g, ln2_b, out);
}

// Round 6
// 137.934 us; speedup vs baseline: 1.9764x; 1.2618x over previous
//
#include <hip/hip_runtime.h>
#include <math.h>

#define BB 8
#define TT 2048
#define DD 32
#define HH 4
#define HD 8
#define NROWS (BB*TT)       // 16384 (B*T); attention rows = B*H*T = 65536
#define LNEPS 1e-5f

#if __has_builtin(__builtin_amdgcn_exp2f)
#define EXP2F(x) __builtin_amdgcn_exp2f(x)
#else
#define EXP2F(x) __expf(0.6931471805599453f*(x))
#endif

typedef _Float16 h2 __attribute__((ext_vector_type(2)));
typedef _Float16 h4v __attribute__((ext_vector_type(4)));
typedef float f4v __attribute__((ext_vector_type(4)));
struct KH { h2 a, b, c, d; };               // 16B: 8 halves
union F4H { float4 f; KH k; };

static __device__ __forceinline__ h2 pkrtz(float a, float b) {
    return __builtin_bit_cast(h2, __builtin_amdgcn_cvt_pkrtz(a, b));
}
static __device__ __forceinline__ unsigned pkrtz_u(float a, float b) {
    return __builtin_bit_cast(unsigned, __builtin_amdgcn_cvt_pkrtz(a, b));
}
static __device__ __forceinline__ unsigned short f16u(float x) {
    return __builtin_bit_cast(unsigned short, (_Float16)x);
}

// ---------------- Kernel 1: LN1 + QKV projection (8 threads/row) ----------------
// sub = idx&7: hh = sub&3 (head), dh = sub>>2 (which 16 input dims to reduce)
__global__ __launch_bounds__(256) void k_ln_qkv(
    const float* __restrict__ x,
    const float* __restrict__ Wq, const float* __restrict__ Wk, const float* __restrict__ Wv,
    const float* __restrict__ g, const float* __restrict__ b,
    float* __restrict__ h, float* __restrict__ qh,
    float* __restrict__ Kh, float* __restrict__ Vt)
{
    __shared__ float sW[3*HH*264];
    __shared__ float sg[DD], sb[DD];
    for (int i = threadIdx.x; i < HH*DD*HD; i += 256) {
        int hd_ = i >> 8, off = i & 255;
        sW[hd_*264 + off]              = Wq[i];
        sW[(4+hd_)*264 + off]          = Wk[i];
        sW[(8+hd_)*264 + off]          = Wv[i];
    }
    if (threadIdx.x < DD) { sg[threadIdx.x] = g[threadIdx.x]; sb[threadIdx.x] = b[threadIdx.x]; }
    __syncthreads();

    int idx = blockIdx.x * 256 + threadIdx.x;     // 0..131071
    int r   = idx >> 3;                           // row 0..16383
    int sub = idx & 7;
    int hh  = sub & 3;
    int dh  = sub >> 2;                           // 0/1 -> dims dh*16..+15
    int bb  = r >> 11, tt = r & 2047;

    float xr[16];
    {
        const float4* xp = (const float4*)(x + (size_t)r * DD + dh*16);
        float4 t0 = xp[0], t1 = xp[1], t2 = xp[2], t3 = xp[3];
        xr[0]=t0.x; xr[1]=t0.y; xr[2]=t0.z; xr[3]=t0.w;
        xr[4]=t1.x; xr[5]=t1.y; xr[6]=t1.z; xr[7]=t1.w;
        xr[8]=t2.x; xr[9]=t2.y; xr[10]=t2.z; xr[11]=t2.w;
        xr[12]=t3.x; xr[13]=t3.y; xr[14]=t3.z; xr[15]=t3.w;
    }
    float s1 = 0.f;
    #pragma unroll
    for (int i = 0; i < 16; ++i) s1 += xr[i];
    s1 += __shfl_xor(s1, 4, 64);
    float mu = s1 * (1.f/DD);
    float sq = 0.f;
    #pragma unroll
    for (int i = 0; i < 16; ++i) { float d = xr[i]-mu; sq += d*d; }
    sq += __shfl_xor(sq, 4, 64);
    float rs = rsqrtf(sq * (1.f/DD) + LNEPS);

    float hr[16];
    #pragma unroll
    for (int i = 0; i < 16; ++i) hr[i] = (xr[i]-mu)*rs*sg[dh*16+i] + sb[dh*16+i];

    {
        float4* hp = (float4*)(h + (size_t)r * DD + dh*16);
        hp[0]=make_float4(hr[0],hr[1],hr[2],hr[3]);
        hp[1]=make_float4(hr[4],hr[5],hr[6],hr[7]);
        hp[2]=make_float4(hr[8],hr[9],hr[10],hr[11]);
        hp[3]=make_float4(hr[12],hr[13],hr[14],hr[15]);
    }

    const float* wq = sW + hh*264 + dh*128;
    const float* wk = sW + (4+hh)*264 + dh*128;
    const float* wv = sW + (8+hh)*264 + dh*128;
    float qa[HD], ka[HD], va[HD];
    #pragma unroll
    for (int k2 = 0; k2 < HD; ++k2) { qa[k2]=0.f; ka[k2]=0.f; va[k2]=0.f; }
    #pragma unroll
    for (int d = 0; d < 16; ++d) {
        float hv = hr[d];
        const float4* wq4 = (const float4*)(wq + d*8);
        const float4* wk4 = (const float4*)(wk + d*8);
        const float4* wv4 = (const float4*)(wv + d*8);
        float4 a0 = wq4[0], a1 = wq4[1];
        float4 b0 = wk4[0], b1 = wk4[1];
        float4 c0 = wv4[0], c1 = wv4[1];
        qa[0]=fmaf(hv,a0.x,qa[0]); qa[1]=fmaf(hv,a0.y,qa[1]); qa[2]=fmaf(hv,a0.z,qa[2]); qa[3]=fmaf(hv,a0.w,qa[3]);
        qa[4]=fmaf(hv,a1.x,qa[4]); qa[5]=fmaf(hv,a1.y,qa[5]); qa[6]=fmaf(hv,a1.z,qa[6]); qa[7]=fmaf(hv,a1.w,qa[7]);
        ka[0]=fmaf(hv,b0.x,ka[0]); ka[1]=fmaf(hv,b0.y,ka[1]); ka[2]=fmaf(hv,b0.z,ka[2]); ka[3]=fmaf(hv,b0.w,ka[3]);
        ka[4]=fmaf(hv,b1.x,ka[4]); ka[5]=fmaf(hv,b1.y,ka[5]); ka[6]=fmaf(hv,b1.z,ka[6]); ka[7]=fmaf(hv,b1.w,ka[7]);
        va[0]=fmaf(hv,c0.x,va[0]); va[1]=fmaf(hv,c0.y,va[1]); va[2]=fmaf(hv,c0.z,va[2]); va[3]=fmaf(hv,c0.w,va[3]);
        va[4]=fmaf(hv,c1.x,va[4]); va[5]=fmaf(hv,c1.y,va[5]); va[6]=fmaf(hv,c1.z,va[6]); va[7]=fmaf(hv,c1.w,va[7]);
    }
    #pragma unroll
    for (int k2 = 0; k2 < HD; ++k2) {
        qa[k2] += __shfl_xor(qa[k2], 4, 64);
        ka[k2] += __shfl_xor(ka[k2], 4, 64);
        va[k2] += __shfl_xor(va[k2], 4, 64);
    }

    const float SCL = 0.35355339059327373f * 1.4426950408889634f;  // 1/sqrt(8)*log2e
    size_t key = (size_t)(bb*HH + hh)*TT + tt;
    unsigned short* vtb = (unsigned short*)Vt + (size_t)(bb*HH + hh)*8*TT + tt;
    if (dh == 0) {
        F4H u;
        u.k.a = pkrtz(qa[0]*SCL, qa[1]*SCL);
        u.k.b = pkrtz(qa[2]*SCL, qa[3]*SCL);
        u.k.c = pkrtz(qa[4]*SCL, qa[5]*SCL);
        u.k.d = pkrtz(qa[6]*SCL, qa[7]*SCL);
        *(float4*)(qh + key*4) = u.f;
        vtb[(size_t)0*TT] = f16u(va[0]);
        vtb[(size_t)1*TT] = f16u(va[1]);
        vtb[(size_t)2*TT] = f16u(va[2]);
        vtb[(size_t)3*TT] = f16u(va[3]);
    } else {
        F4H u;
        u.k.a = pkrtz(ka[0], ka[1]);
        u.k.b = pkrtz(ka[2], ka[3]);
        u.k.c = pkrtz(ka[4], ka[5]);
        u.k.d = pkrtz(ka[6], ka[7]);
        *(float4*)(Kh + key*4) = u.f;
        vtb[(size_t)4*TT] = f16u(va[4]);
        vtb[(size_t)5*TT] = f16u(va[5]);
        vtb[(size_t)6*TT] = f16u(va[6]);
        vtb[(size_t)7*TT] = f16u(va[7]);
    }
}

// ---------------- Kernel 2: MFMA flash attention ----------------
// Wave = 16 queries. Chunk = 16 keys. Swapped QK^T: S^T = mfma(A=K, B=Q) puts
// P[q=lane&15][s=4g+r] exactly in the A-fragment layout for O += mfma(P, V).
// LDS per tile: K[64 keys][8]f16 (1KB) + Vt[8 d][64 s]f16 XOR-swizzled (1KB).
__global__ __launch_bounds__(256) void k_attn(
    const float* __restrict__ qh, const float* __restrict__ Kh,
    const float* __restrict__ Vt, float* __restrict__ o)
{
    __shared__ char lds[2][2048];               // [buf]: K 0..1023 | Vt 1024..2047
    const int tid  = threadIdx.x;
    const int wave = tid >> 6;
    const int lane = tid & 63;
    const int g    = lane >> 4;
    const int qi   = lane & 15;
    const int bh   = blockIdx.x & 31;
    const int qblk = 31 - (int)(blockIdx.x >> 5);   // heavy blocks first
    const int qb   = qblk << 6;
    const int wq0  = qb + (wave << 4);
    const int ntiles = qblk + 1;

    const float4*  KbF = (const float4*)Kh + (size_t)bh * TT;     // 16B per key
    const ushort*  VtU = (const ushort*)Vt + (size_t)bh * 8 * TT;

    // Q fragment: B[k=4g+i][col=q]; k>=8 lanes are zero (hd=8 pad)
    h4v qf;
    {
        uint2 qraw = make_uint2(0u, 0u);
        if (g < 2)
            qraw = *(const uint2*)((const ushort*)qh + ((size_t)bh*TT + wq0 + qi)*8 + (size_t)(g<<2));
        qf = __builtin_bit_cast(h4v, qraw);
    }

    f4v acc = {0.f, 0.f, 0.f, 0.f};
    float m = 0.f, l = 0.f;

    // stage tile 0 (V staged with inverse-swizzled SOURCE, linear LDS write)
    float4 st = make_float4(0.f,0.f,0.f,0.f);
    if (tid < 64) {
        st = KbF[tid];
    } else if (tid < 128) {
        int t2 = tid - 64, d = t2 >> 3, seg = (t2 & 7) ^ d;
        st = *(const float4*)(VtU + (size_t)d*TT + (seg << 3));
    }
    if (tid < 64)       *(float4*)(&lds[0][0] + tid*16) = st;
    else if (tid < 128) *(float4*)(&lds[0][0] + 1024 + (tid-64)*16) = st;
    __syncthreads();

    int buf = 0;
    for (int t = 0; t < ntiles; ++t) {
        const int tb = t << 6;
        float4 nx = make_float4(0.f,0.f,0.f,0.f);
        const bool more = (t + 1 < ntiles);
        if (more) {                                  // issue next-tile loads EARLY
            const int nb = (t + 1) << 6;
            if (tid < 64) nx = KbF[nb + tid];
            else if (tid < 128) {
                int t2 = tid - 64, d = t2 >> 3, seg = (t2 & 7) ^ d;
                nx = *(const float4*)(VtU + (size_t)d*TT + nb + (seg << 3));
            }
        }
        const char* smK = &lds[buf][0];
        const char* smV = &lds[buf][0] + 1024;
        #pragma unroll
        for (int c = 0; c < 4; ++c) {
            const int s0 = tb + (c << 4);
            if (s0 > wq0) continue;                  // beyond causal range for this wave
            const bool diag = (s0 == wq0);

            // K fragment: A[row=s=qi][k=4g+i]; k>=8 lanes zeroed
            uint2 kraw = *(const uint2*)(smK + ((c<<4) + qi)*16 + ((g&1)<<3));
            if (g >= 2) { kraw.x = 0u; kraw.y = 0u; }
            h4v kf = __builtin_bit_cast(h4v, kraw);

            // V fragment: B[k=s=4g+i][col=d=qi] from swizzled Vt tile
            const int d7 = lane & 7;
            uint2 vraw = *(const uint2*)(smV + d7*128 + (((c<<5) + (g<<3)) ^ (d7<<4)));
            h4v vf = __builtin_bit_cast(h4v, vraw);

            f4v Z = {0.f,0.f,0.f,0.f};
            f4v S = __builtin_amdgcn_mfma_f32_16x16x16f16(kf, qf, Z, 0, 0, 0);

            float dd[4];
            #pragma unroll
            for (int r = 0; r < 4; ++r) {
                float v = S[r];
                if (diag && ((g<<2) + r > qi)) v = -1e30f;   // causal mask (static)
                dd[r] = v;
            }
            float pm = fmaxf(fmaxf(dd[0], dd[1]), fmaxf(dd[2], dd[3]));
            pm = fmaxf(pm, __shfl_xor(pm, 16, 64));
            pm = fmaxf(pm, __shfl_xor(pm, 32, 64));
            if (__builtin_expect(__any(pm - m > 8.f), 0)) {  // defer-max, rare
                float mn = fmaxf(m, pm);
                float cr = EXP2F(m - mn);
                l *= cr;
                #pragma unroll
                for (int r = 0; r < 4; ++r) {
                    float c4 = __shfl(cr, (g<<2) + r, 64);   // remap q-lanes -> O layout
                    acc[r] *= c4;
                }
                m = mn;
            }
            float p0 = EXP2F(dd[0] - m);
            float p1 = EXP2F(dd[1] - m);
            float p2 = EXP2F(dd[2] - m);
            float p3 = EXP2F(dd[3] - m);
            l += (p0 + p1) + (p2 + p3);
            uint2 pu; pu.x = pkrtz_u(p0, p1); pu.y = pkrtz_u(p2, p3);
            h4v pf = __builtin_bit_cast(h4v, pu);
            acc = __builtin_amdgcn_mfma_f32_16x16x16f16(pf, vf, acc, 0, 0, 0);
        }
        if (more) {                                  // write LATE
            if (tid < 64)       *(float4*)(&lds[buf^1][0] + tid*16) = nx;
            else if (tid < 128) *(float4*)(&lds[buf^1][0] + 1024 + (tid-64)*16) = nx;
        }
        __syncthreads();
        buf ^= 1;
    }

    // finalize: O is already fully summed by mfma; just normalize
    l += __shfl_xor(l, 16, 64);
    l += __shfl_xor(l, 32, 64);
    float Linv = 1.f / l;
    float Li[4];
    #pragma unroll
    for (int r = 0; r < 4; ++r) Li[r] = __shfl(Linv, (g<<2) + r, 64);
    if (qi < HD) {
        float* ob = o + ((size_t)bh*TT + wq0)*HD + qi;
        #pragma unroll
        for (int r = 0; r < 4; ++r)
            ob[(size_t)((g<<2) + r) * HD] = acc[r] * Li[r];
    }
}

// ---------------- Kernel 3: proj + residual + LN2 + FFN (8 threads/row) ----------
__global__ __launch_bounds__(256) void k_proj_ffn(
    const float* __restrict__ h, const float* __restrict__ o,
    const float* __restrict__ Wproj, const float* __restrict__ bproj,
    const float* __restrict__ W1, const float* __restrict__ b1,
    const float* __restrict__ W2, const float* __restrict__ b2,
    const float* __restrict__ g2, const float* __restrict__ bt2,
    float* __restrict__ out)
{
    __shared__ float sWp[DD*36], sW1T[4*DD*36], sW2[4*DD*36];
    __shared__ float sbp[DD], sb1[4*DD], sb2[DD], sg2[DD], sbt2[DD];
    for (int i = threadIdx.x; i < DD*DD; i += 256)      sWp [(i>>5)*36 + (i&31)] = Wproj[i];
    for (int i = threadIdx.x; i < DD*4*DD; i += 256) {
        sW1T[(i&127)*36 + (i>>7)] = W1[i];
        sW2 [(i>>5)*36 + (i&31)]  = W2[i];
    }
    if (threadIdx.x < DD) {
        sbp[threadIdx.x]  = bproj[threadIdx.x];
        sb2[threadIdx.x]  = b2[threadIdx.x];
        sg2[threadIdx.x]  = g2[threadIdx.x];
        sbt2[threadIdx.x] = bt2[threadIdx.x];
    }
    if (threadIdx.x < 4*DD) sb1[threadIdx.x] = b1[threadIdx.x];
    __syncthreads();

    int idx = blockIdx.x * 256 + threadIdx.x;
    int r   = idx >> 3;
    int sub = idx & 7;
    int bb  = r >> 11, tt = r & 2047;

    float o4[4];
    #pragma unroll
    for (int mm = 0; mm < 4; ++mm)
        o4[mm] = o[((size_t)(bb*HH + mm)*TT + tt) * HD + sub];

    float x1[DD];
    #pragma unroll
    for (int d = 0; d < DD; ++d) x1[d] = 0.f;
    #pragma unroll
    for (int mm = 0; mm < 4; ++mm) {
        const float4* wr = (const float4*)&sWp[(sub + 8*mm)*36];
        float ov = o4[mm];
        #pragma unroll
        for (int dc = 0; dc < 8; ++dc) {
            float4 w4 = wr[dc];
            x1[4*dc]   = fmaf(ov, w4.x, x1[4*dc]);
            x1[4*dc+1] = fmaf(ov, w4.y, x1[4*dc+1]);
            x1[4*dc+2] = fmaf(ov, w4.z, x1[4*dc+2]);
            x1[4*dc+3] = fmaf(ov, w4.w, x1[4*dc+3]);
        }
    }
    #pragma unroll
    for (int d = 0; d < DD; ++d) {
        x1[d] += __shfl_xor(x1[d], 1, 64);
        x1[d] += __shfl_xor(x1[d], 2, 64);
        x1[d] += __shfl_xor(x1[d], 4, 64);
    }
    {
        const float4* hp = (const float4*)(h + (size_t)r * DD);
        #pragma unroll
        for (int dc = 0; dc < 8; ++dc) {
            float4 h4 = hp[dc];
            x1[4*dc]   += h4.x + sbp[4*dc];
            x1[4*dc+1] += h4.y + sbp[4*dc+1];
            x1[4*dc+2] += h4.z + sbp[4*dc+2];
            x1[4*dc+3] += h4.w + sbp[4*dc+3];
        }
    }
    float mu = 0.f;
    #pragma unroll
    for (int d = 0; d < DD; ++d) mu += x1[d];
    mu *= (1.f/DD);
    float var = 0.f;
    #pragma unroll
    for (int d = 0; d < DD; ++d) { float dl = x1[d]-mu; var += dl*dl; }
    var *= (1.f/DD);
    float rs = rsqrtf(var + LNEPS);
    float h2v[DD];
    #pragma unroll
    for (int d = 0; d < DD; ++d) h2v[d] = (x1[d]-mu)*rs*sg2[d] + sbt2[d];

    float outp[DD];
    #pragma unroll
    for (int d = 0; d < DD; ++d) outp[d] = 0.f;
    #pragma unroll
    for (int mm = 0; mm < 16; ++mm) {
        int j = sub + 8*mm;
        const float4* w1r = (const float4*)&sW1T[j*36];
        float a = sb1[j];
        #pragma unroll
        for (int dc = 0; dc < 8; ++dc) {
            float4 w4 = w1r[dc];
            a = fmaf(h2v[4*dc], w4.x, a);
            a = fmaf(h2v[4*dc+1], w4.y, a);
            a = fmaf(h2v[4*dc+2], w4.z, a);
            a = fmaf(h2v[4*dc+3], w4.w, a);
        }
        a = fmaxf(a, 0.f);
        const float4* w2r = (const float4*)&sW2[j*36];
        #pragma unroll
        for (int dc = 0; dc < 8; ++dc) {
            float4 w4 = w2r[dc];
            outp[4*dc]   = fmaf(a, w4.x, outp[4*dc]);
            outp[4*dc+1] = fmaf(a, w4.y, outp[4*dc+1]);
            outp[4*dc+2] = fmaf(a, w4.z, outp[4*dc+2]);
            outp[4*dc+3] = fmaf(a, w4.w, outp[4*dc+3]);
        }
    }
    if (sub == 0) {
        #pragma unroll
        for (int d = 0; d < DD; ++d) outp[d] += h2v[d] + sb2[d];
    }
    float t1[16];
    #pragma unroll
    for (int i = 0; i < 16; ++i) {
        bool hi = (sub & 4) != 0;
        float send = hi ? outp[i] : outp[i+16];
        float recv = __shfl_xor(send, 4, 64);
        t1[i] = (hi ? outp[i+16] : outp[i]) + recv;
    }
    float t2[8];
    #pragma unroll
    for (int i = 0; i < 8; ++i) {
        bool hi = (sub & 2) != 0;
        float send = hi ? t1[i] : t1[i+8];
        float recv = __shfl_xor(send, 2, 64);
        t2[i] = (hi ? t1[i+8] : t1[i]) + recv;
    }
    float w0[4];
    #pragma unroll
    for (int i = 0; i < 4; ++i) {
        bool hi = (sub & 1) != 0;
        float send = hi ? t2[i] : t2[i+4];
        float recv = __shfl_xor(send, 1, 64);
        w0[i] = (hi ? t2[i+4] : t2[i]) + recv;
    }
    *(float4*)(out + (size_t)r * DD + sub*4) = make_float4(w0[0], w0[1], w0[2], w0[3]);
}

extern "C" void kernel_launch(void* const* d_in, const int* in_sizes, int n_in,
                              void* d_out, int out_size, void* d_ws, size_t ws_size,
                              hipStream_t stream) {
    const float* x     = (const float*)d_in[0];
    const float* Wq    = (const float*)d_in[1];
    const float* Wk    = (const float*)d_in[2];
    const float* Wv    = (const float*)d_in[3];
    const float* Wproj = (const float*)d_in[4];
    const float* bproj = (const float*)d_in[5];
    const float* ln1_g = (const float*)d_in[6];
    const float* ln1_b = (const float*)d_in[7];
    const float* W1    = (const float*)d_in[8];
    const float* b1    = (const float*)d_in[9];
    const float* W2    = (const float*)d_in[10];
    const float* b2    = (const float*)d_in[11];
    const float* ln2_g = (const float*)d_in[12];
    const float* ln2_b = (const float*)d_in[13];
    float* out = (float*)d_out;

    const size_t N = (size_t)NROWS * DD;   // 524288
    const size_t K = (size_t)BB*HH*TT*4;   // 262144 (16B per attn row as floats)
    float* ws = (float*)d_ws;
    float* h  = ws;                        // N   f32
    float* qh = ws + N;                    // K   f16x8 per row (scaled by 1/sqrt(hd)*log2e)
    float* Kh = ws + N + K;                // K   f16x8 per key
    float* Vt = ws + N + 2*K;              // K   f16 transposed [bh][d][t]
    float* o  = ws + N + 3*K;              // N   f32 [bh][t][8]

    k_ln_qkv  <<<512, 256, 0, stream>>>(x, Wq, Wk, Wv, ln1_g, ln1_b, h, qh, Kh, Vt);
    k_attn    <<<1024, 256, 0, stream>>>(qh, Kh, Vt, o);
    k_proj_ffn<<<512, 256, 0, stream>>>(h, o, Wproj, bproj, W1, b1, W2, b2, ln2_g, ln2_b, out);
}

// Round 7
// 137.666 us; speedup vs baseline: 1.9803x; 1.0019x over previous
//
#include <hip/hip_runtime.h>
#include <math.h>

#define BB 8
#define TT 2048
#define DD 32
#define HH 4
#define HD 8
#define NROWS (BB*TT)       // 16384 (B*T); attention rows = B*H*T = 65536
#define LNEPS 1e-5f

#if __has_builtin(__builtin_amdgcn_exp2f)
#define EXP2F(x) __builtin_amdgcn_exp2f(x)
#else
#define EXP2F(x) __expf(0.6931471805599453f*(x))
#endif

typedef _Float16 h2 __attribute__((ext_vector_type(2)));
typedef _Float16 h4v __attribute__((ext_vector_type(4)));
typedef _Float16 h8v __attribute__((ext_vector_type(8)));
typedef float f32x16 __attribute__((ext_vector_type(16)));
struct KH { h2 a, b, c, d; };               // 16B: 8 halves
union F4H { float4 f; KH k; };

static __device__ __forceinline__ h2 pkrtz(float a, float b) {
    return __builtin_bit_cast(h2, __builtin_amdgcn_cvt_pkrtz(a, b));
}
static __device__ __forceinline__ unsigned pkrtz_u(float a, float b) {
    return __builtin_bit_cast(unsigned, __builtin_amdgcn_cvt_pkrtz(a, b));
}
static __device__ __forceinline__ unsigned short f16u(float x) {
    return __builtin_bit_cast(unsigned short, (_Float16)x);
}

#if __has_builtin(__builtin_amdgcn_fdot2)
#define DOT2(a,b,c) __builtin_amdgcn_fdot2((a),(b),(c),false)
#else
#define DOT2(a,b,c) fmaf((float)(a)[1],(float)(b)[1], fmaf((float)(a)[0],(float)(b)[0],(c)))
#endif

// ---------------- Kernel 1: LN1 + QKV projection (8 threads/row) ----------------
// sub = idx&7: hh = sub&3 (head), dh = sub>>2 (which 16 input dims to reduce)
__global__ __launch_bounds__(256) void k_ln_qkv(
    const float* __restrict__ x,
    const float* __restrict__ Wq, const float* __restrict__ Wk, const float* __restrict__ Wv,
    const float* __restrict__ g, const float* __restrict__ b,
    float* __restrict__ h, float* __restrict__ qh,
    float* __restrict__ Kh, float* __restrict__ Vt)
{
    __shared__ float sW[3*HH*264];
    __shared__ float sg[DD], sb[DD];
    for (int i = threadIdx.x; i < HH*DD*HD; i += 256) {
        int hd_ = i >> 8, off = i & 255;
        sW[hd_*264 + off]              = Wq[i];
        sW[(4+hd_)*264 + off]          = Wk[i];
        sW[(8+hd_)*264 + off]          = Wv[i];
    }
    if (threadIdx.x < DD) { sg[threadIdx.x] = g[threadIdx.x]; sb[threadIdx.x] = b[threadIdx.x]; }
    __syncthreads();

    int idx = blockIdx.x * 256 + threadIdx.x;     // 0..131071
    int r   = idx >> 3;                           // row 0..16383
    int sub = idx & 7;
    int hh  = sub & 3;
    int dh  = sub >> 2;                           // 0/1 -> dims dh*16..+15
    int bb  = r >> 11, tt = r & 2047;

    float xr[16];
    {
        const float4* xp = (const float4*)(x + (size_t)r * DD + dh*16);
        float4 t0 = xp[0], t1 = xp[1], t2 = xp[2], t3 = xp[3];
        xr[0]=t0.x; xr[1]=t0.y; xr[2]=t0.z; xr[3]=t0.w;
        xr[4]=t1.x; xr[5]=t1.y; xr[6]=t1.z; xr[7]=t1.w;
        xr[8]=t2.x; xr[9]=t2.y; xr[10]=t2.z; xr[11]=t2.w;
        xr[12]=t3.x; xr[13]=t3.y; xr[14]=t3.z; xr[15]=t3.w;
    }
    float s1 = 0.f;
    #pragma unroll
    for (int i = 0; i < 16; ++i) s1 += xr[i];
    s1 += __shfl_xor(s1, 4, 64);
    float mu = s1 * (1.f/DD);
    float sq = 0.f;
    #pragma unroll
    for (int i = 0; i < 16; ++i) { float d = xr[i]-mu; sq += d*d; }
    sq += __shfl_xor(sq, 4, 64);
    float rs = rsqrtf(sq * (1.f/DD) + LNEPS);

    float hr[16];
    #pragma unroll
    for (int i = 0; i < 16; ++i) hr[i] = (xr[i]-mu)*rs*sg[dh*16+i] + sb[dh*16+i];

    {
        float4* hp = (float4*)(h + (size_t)r * DD + dh*16);
        hp[0]=make_float4(hr[0],hr[1],hr[2],hr[3]);
        hp[1]=make_float4(hr[4],hr[5],hr[6],hr[7]);
        hp[2]=make_float4(hr[8],hr[9],hr[10],hr[11]);
        hp[3]=make_float4(hr[12],hr[13],hr[14],hr[15]);
    }

    const float* wq = sW + hh*264 + dh*128;
    const float* wk = sW + (4+hh)*264 + dh*128;
    const float* wv = sW + (8+hh)*264 + dh*128;
    float qa[HD], ka[HD], va[HD];
    #pragma unroll
    for (int k2 = 0; k2 < HD; ++k2) { qa[k2]=0.f; ka[k2]=0.f; va[k2]=0.f; }
    #pragma unroll
    for (int d = 0; d < 16; ++d) {
        float hv = hr[d];
        const float4* wq4 = (const float4*)(wq + d*8);
        const float4* wk4 = (const float4*)(wk + d*8);
        const float4* wv4 = (const float4*)(wv + d*8);
        float4 a0 = wq4[0], a1 = wq4[1];
        float4 b0 = wk4[0], b1 = wk4[1];
        float4 c0 = wv4[0], c1 = wv4[1];
        qa[0]=fmaf(hv,a0.x,qa[0]); qa[1]=fmaf(hv,a0.y,qa[1]); qa[2]=fmaf(hv,a0.z,qa[2]); qa[3]=fmaf(hv,a0.w,qa[3]);
        qa[4]=fmaf(hv,a1.x,qa[4]); qa[5]=fmaf(hv,a1.y,qa[5]); qa[6]=fmaf(hv,a1.z,qa[6]); qa[7]=fmaf(hv,a1.w,qa[7]);
        ka[0]=fmaf(hv,b0.x,ka[0]); ka[1]=fmaf(hv,b0.y,ka[1]); ka[2]=fmaf(hv,b0.z,ka[2]); ka[3]=fmaf(hv,b0.w,ka[3]);
        ka[4]=fmaf(hv,b1.x,ka[4]); ka[5]=fmaf(hv,b1.y,ka[5]); ka[6]=fmaf(hv,b1.z,ka[6]); ka[7]=fmaf(hv,b1.w,ka[7]);
        va[0]=fmaf(hv,c0.x,va[0]); va[1]=fmaf(hv,c0.y,va[1]); va[2]=fmaf(hv,c0.z,va[2]); va[3]=fmaf(hv,c0.w,va[3]);
        va[4]=fmaf(hv,c1.x,va[4]); va[5]=fmaf(hv,c1.y,va[5]); va[6]=fmaf(hv,c1.z,va[6]); va[7]=fmaf(hv,c1.w,va[7]);
    }
    #pragma unroll
    for (int k2 = 0; k2 < HD; ++k2) {
        qa[k2] += __shfl_xor(qa[k2], 4, 64);
        ka[k2] += __shfl_xor(ka[k2], 4, 64);
        va[k2] += __shfl_xor(va[k2], 4, 64);
    }

    const float SCL = 0.35355339059327373f * 1.4426950408889634f;  // 1/sqrt(8)*log2e
    size_t key = (size_t)(bb*HH + hh)*TT + tt;
    char* Vb8 = (char*)Vt + (size_t)(bb*HH + hh)*32768;
    int t6 = tt >> 6, tr = (tt & 63) << 1;
    char* vrow = Vb8 + t6*128;
    if (dh == 0) {
        F4H u;
        u.k.a = pkrtz(qa[0]*SCL, qa[1]*SCL);
        u.k.b = pkrtz(qa[2]*SCL, qa[3]*SCL);
        u.k.c = pkrtz(qa[4]*SCL, qa[5]*SCL);
        u.k.d = pkrtz(qa[6]*SCL, qa[7]*SCL);
        *(float4*)(qh + key*4) = u.f;
        // V^T rows 0..3, XOR(d<<4) pre-swizzled within 64-key tile
        *(unsigned short*)(vrow + 0*4096 + (tr ^ 0))   = f16u(va[0]);
        *(unsigned short*)(vrow + 1*4096 + (tr ^ 16))  = f16u(va[1]);
        *(unsigned short*)(vrow + 2*4096 + (tr ^ 32))  = f16u(va[2]);
        *(unsigned short*)(vrow + 3*4096 + (tr ^ 48))  = f16u(va[3]);
    } else {
        // K fragment-major: plane0 = halves 0-3, plane1 = halves 4-7
        char* Kb8 = (char*)Kh + (size_t)(bb*HH + hh)*32768;
        uint2 k01; k01.x = pkrtz_u(ka[0],ka[1]); k01.y = pkrtz_u(ka[2],ka[3]);
        uint2 k23; k23.x = pkrtz_u(ka[4],ka[5]); k23.y = pkrtz_u(ka[6],ka[7]);
        *(uint2*)(Kb8 + (size_t)tt*8) = k01;
        *(uint2*)(Kb8 + 16384 + (size_t)tt*8) = k23;
        *(unsigned short*)(vrow + 4*4096 + (tr ^ 64))  = f16u(va[4]);
        *(unsigned short*)(vrow + 5*4096 + (tr ^ 80))  = f16u(va[5]);
        *(unsigned short*)(vrow + 6*4096 + (tr ^ 96))  = f16u(va[6]);
        *(unsigned short*)(vrow + 7*4096 + (tr ^ 112)) = f16u(va[7]);
    }
}

// ---------------- Kernel 2: 32x32 MFMA flash attention ----------------
// Wave = 32 queries; chunk = 32 keys: S^T = mfma_32x32x8(A=K, B=Q, C=-m) (hd=8 = K, no pad).
// P repacked (cvt_pk + shfl_xor(32)) into A-frag for O += mfma_32x32x16(P, V).
// Block = 4 waves: 2 q-groups x 2 key-parities; merge via LDS epilogue.
template<bool DIAG>
__device__ __forceinline__ void do_chunk(
    const char* __restrict__ smK, const char* __restrict__ smV,
    int kc, int hi, int col, h4v qf,
    float& m, float& l, f32x16& acc)
{
    // K A-frag: row=key=col? no: row = lane&31 -> key kc+(lane&31); k-halves = plane hi
    uint2 kraw = *(const uint2*)(smK + hi*512 + (size_t)(kc + col)*8);
    h4v kf = __builtin_bit_cast(h4v, kraw);
    f32x16 cin;
    #pragma unroll
    for (int r2 = 0; r2 < 16; ++r2) cin[r2] = -m;
    f32x16 S = __builtin_amdgcn_mfma_f32_32x32x8f16(kf, qf, cin, 0, 0, 0);
    if (DIAG) {
        #pragma unroll
        for (int r2 = 0; r2 < 16; ++r2) {
            int row = (r2&3) + 8*(r2>>2) + 4*hi;
            if (row > col) S[r2] = -1e30f;
        }
    }
    float pm = S[0];
    #pragma unroll
    for (int r2 = 1; r2 < 16; ++r2) pm = fmaxf(pm, S[r2]);
    pm = fmaxf(pm, __shfl_xor(pm, 32, 64));
    if (__builtin_expect(__any(pm > 8.f), 0)) {       // defer-max: rare rescale
        float adj = fmaxf(pm, 0.f);
        float cr  = EXP2F(-adj);
        l *= cr;
        #pragma unroll
        for (int r2 = 0; r2 < 16; ++r2) {
            int row = (r2&3) + 8*(r2>>2) + 4*hi;
            acc[r2] *= __shfl(cr, row, 64);
        }
        #pragma unroll
        for (int r2 = 0; r2 < 16; ++r2) S[r2] -= adj;
        m += adj;
    }
    float p[16];
    #pragma unroll
    for (int r2 = 0; r2 < 16; ++r2) p[r2] = EXP2F(S[r2]);
    unsigned pa_ = pkrtz_u(p[0],  p[1]);
    unsigned pb_ = pkrtz_u(p[2],  p[3]);
    unsigned pc_ = pkrtz_u(p[4],  p[5]);
    unsigned pd_ = pkrtz_u(p[6],  p[7]);
    unsigned pe_ = pkrtz_u(p[8],  p[9]);
    unsigned pf_ = pkrtz_u(p[10], p[11]);
    unsigned pg_ = pkrtz_u(p[12], p[13]);
    unsigned ph_ = pkrtz_u(p[14], p[15]);
    const h2 one2 = {(_Float16)1.f, (_Float16)1.f};
    l = DOT2(__builtin_bit_cast(h2, pa_), one2, l);
    l = DOT2(__builtin_bit_cast(h2, pb_), one2, l);
    l = DOT2(__builtin_bit_cast(h2, pc_), one2, l);
    l = DOT2(__builtin_bit_cast(h2, pd_), one2, l);
    l = DOT2(__builtin_bit_cast(h2, pe_), one2, l);
    l = DOT2(__builtin_bit_cast(h2, pf_), one2, l);
    l = DOT2(__builtin_bit_cast(h2, pg_), one2, l);
    l = DOT2(__builtin_bit_cast(h2, ph_), one2, l);
    unsigned ra = (unsigned)__shfl_xor((int)pa_, 32, 64);
    unsigned rb = (unsigned)__shfl_xor((int)pb_, 32, 64);
    unsigned rc = (unsigned)__shfl_xor((int)pc_, 32, 64);
    unsigned rd = (unsigned)__shfl_xor((int)pd_, 32, 64);
    unsigned re = (unsigned)__shfl_xor((int)pe_, 32, 64);
    unsigned rf = (unsigned)__shfl_xor((int)pf_, 32, 64);
    unsigned rg = (unsigned)__shfl_xor((int)pg_, 32, 64);
    unsigned rh = (unsigned)__shfl_xor((int)ph_, 32, 64);
    bool H = (hi != 0);
    uint4 A0 = { H?rc:pa_, H?rd:pb_, H?pc_:ra, H?pd_:rb };   // PV keys kc+0..15
    uint4 A1 = { H?rg:pe_, H?rh:pf_, H?pg_:re, H?ph_:rf };   // PV keys kc+16..31
    int d7 = col & 7;
    const char* vrow = smV + d7*128;
    uint4 v0 = *(const uint4*)(vrow + ((((kc + hi*8) << 1)) ^ (d7 << 4)));
    uint4 v1 = *(const uint4*)(vrow + ((((kc + 16 + hi*8) << 1)) ^ (d7 << 4)));
    acc = __builtin_amdgcn_mfma_f32_32x32x16_f16(
        __builtin_bit_cast(h8v, A0), __builtin_bit_cast(h8v, v0), acc, 0, 0, 0);
    acc = __builtin_amdgcn_mfma_f32_32x32x16_f16(
        __builtin_bit_cast(h8v, A1), __builtin_bit_cast(h8v, v1), acc, 0, 0, 0);
}

__global__ __launch_bounds__(256) void k_attn(
    const float* __restrict__ qh, const float* __restrict__ Kh,
    const float* __restrict__ Vt, float* __restrict__ o)
{
    __shared__ char lds[7168];   // [0,4096): dbuf 2x(K 1KB | V 1KB); mbuf; lbuf; obuf
    const int tid  = threadIdx.x;
    const int wave = tid >> 6;
    const int lane = tid & 63;
    const int hi   = lane >> 5;
    const int col  = lane & 31;
    const int qg   = wave >> 1;               // q-group within block
    const int kh   = wave & 1;                // key parity
    const int bh   = blockIdx.x & 31;
    const int qblk = 31 - (int)(blockIdx.x >> 5);    // heavy blocks first
    const int qb   = qblk << 6;
    const int wq0  = qb + (qg << 5);
    const int ntiles = qblk + 1;              // 64-key tiles

    const char* Kg = (const char*)Kh + (size_t)bh * 32768;
    const char* Vg = (const char*)Vt + (size_t)bh * 32768;
    const char* Qg = (const char*)qh + (size_t)bh * 32768 + (size_t)wq0 * 16;

    // Q B-frag: col = query, k = 4*hi + i
    h4v qf = __builtin_bit_cast(h4v, *(const uint2*)(Qg + col*16 + hi*8));

    f32x16 acc;
    #pragma unroll
    for (int r2 = 0; r2 < 16; ++r2) acc[r2] = 0.f;
    float m = 0.f, l = 0.f;

    // prologue: stage tile 0
    {
        uint4 st;
        if (tid < 64)       st = *(const uint4*)(Kg + (tid>>5)*16384 + (size_t)(tid&31)*16);
        else if (tid < 128) { int ix = tid-64; st = *(const uint4*)(Vg + (ix>>3)*4096 + (ix&7)*16); }
        if (tid < 64)       *(uint4*)(&lds[0] + (tid>>5)*512 + (tid&31)*16) = st;
        else if (tid < 128) *(uint4*)(&lds[0] + 1024 + (tid-64)*16) = st;
    }
    __syncthreads();

    int buf = 0;
    for (int t = 0; t < ntiles; ++t) {
        uint4 nx;
        const bool more = (t + 1 < ntiles);
        if (more) {                                       // issue next-tile loads EARLY
            if (tid < 64)       nx = *(const uint4*)(Kg + (tid>>5)*16384 + (t+1)*512 + (tid&31)*16);
            else if (tid < 128) { int ix = tid-64; nx = *(const uint4*)(Vg + (ix>>3)*4096 + (t+1)*128 + (ix&7)*16); }
        }
        if ((t & 1) == kh) {                              // this wave's key parity
            const int tb = t << 6;
            const char* smK = &lds[buf*2048];
            const char* smV = smK + 1024;
            if (tb <= wq0) {
                if (tb == wq0) do_chunk<true >(smK, smV, 0, hi, col, qf, m, l, acc);
                else           do_chunk<false>(smK, smV, 0, hi, col, qf, m, l, acc);
                if (tb + 32 <= wq0) {
                    if (tb + 32 == wq0) do_chunk<true >(smK, smV, 32, hi, col, qf, m, l, acc);
                    else                do_chunk<false>(smK, smV, 32, hi, col, qf, m, l, acc);
                }
            }
        }
        if (more) {                                       // write LATE
            if (tid < 64)       *(uint4*)(&lds[(buf^1)*2048] + (tid>>5)*512 + (tid&31)*16) = nx;
            else if (tid < 128) *(uint4*)(&lds[(buf^1)*2048] + 1024 + (tid-64)*16) = nx;
        }
        __syncthreads();
        buf ^= 1;
    }

    // ---- merge the two key-parity waves of this q-group ----
    l += __shfl_xor(l, 32, 64);                 // wave-total per query
    float* mb = (float*)&lds[4096];
    float* lb = (float*)&lds[4608];
    float* ob = (float*)&lds[5120];
    if (lane < 32) {
        mb[(kh<<6) + (qg<<5) + col] = m;
        lb[(kh<<6) + (qg<<5) + col] = l;
    }
    __syncthreads();
    float mo = mb[((kh^1)<<6) + (qg<<5) + col];
    float lo = lb[((kh^1)<<6) + (qg<<5) + col];
    float M  = fmaxf(m, mo);
    float fs = EXP2F(m - M);
    float L  = l * fs + lo * EXP2F(mo - M);
    float Linv = 1.f / L;
    float fr[16], Lr[16];
    #pragma unroll
    for (int r2 = 0; r2 < 16; ++r2) {
        int row = (r2&3) + 8*(r2>>2) + 4*hi;
        fr[r2] = __shfl(fs,   row, 64);
        Lr[r2] = __shfl(Linv, row, 64);
    }
    if (kh == 1 && col < HD) {
        #pragma unroll
        for (int r2 = 0; r2 < 16; ++r2) {
            int row = (r2&3) + 8*(r2>>2) + 4*hi;
            ob[(qg<<8) + (row<<3) + col] = acc[r2] * fr[r2];
        }
    }
    __syncthreads();
    if (kh == 0 && col < HD) {
        float* og = o + ((size_t)bh*TT + wq0)*HD + col;
        #pragma unroll
        for (int r2 = 0; r2 < 16; ++r2) {
            int row = (r2&3) + 8*(r2>>2) + 4*hi;
            og[(size_t)row * HD] = (acc[r2]*fr[r2] + ob[(qg<<8) + (row<<3) + col]) * Lr[r2];
        }
    }
}

// ---------------- Kernel 3: proj + residual + LN2 + FFN (8 threads/row) ----------
__global__ __launch_bounds__(256) void k_proj_ffn(
    const float* __restrict__ h, const float* __restrict__ o,
    const float* __restrict__ Wproj, const float* __restrict__ bproj,
    const float* __restrict__ W1, const float* __restrict__ b1,
    const float* __restrict__ W2, const float* __restrict__ b2,
    const float* __restrict__ g2, const float* __restrict__ bt2,
    float* __restrict__ out)
{
    __shared__ float sWp[DD*36], sW1T[4*DD*36], sW2[4*DD*36];
    __shared__ float sbp[DD], sb1[4*DD], sb2[DD], sg2[DD], sbt2[DD];
    for (int i = threadIdx.x; i < DD*DD; i += 256)      sWp [(i>>5)*36 + (i&31)] = Wproj[i];
    for (int i = threadIdx.x; i < DD*4*DD; i += 256) {
        sW1T[(i&127)*36 + (i>>7)] = W1[i];
        sW2 [(i>>5)*36 + (i&31)]  = W2[i];
    }
    if (threadIdx.x < DD) {
        sbp[threadIdx.x]  = bproj[threadIdx.x];
        sb2[threadIdx.x]  = b2[threadIdx.x];
        sg2[threadIdx.x]  = g2[threadIdx.x];
        sbt2[threadIdx.x] = bt2[threadIdx.x];
    }
    if (threadIdx.x < 4*DD) sb1[threadIdx.x] = b1[threadIdx.x];
    __syncthreads();

    int idx = blockIdx.x * 256 + threadIdx.x;
    int r   = idx >> 3;
    int sub = idx & 7;
    int bb  = r >> 11, tt = r & 2047;

    float o4[4];
    #pragma unroll
    for (int mm = 0; mm < 4; ++mm)
        o4[mm] = o[((size_t)(bb*HH + mm)*TT + tt) * HD + sub];

    float x1[DD];
    #pragma unroll
    for (int d = 0; d < DD; ++d) x1[d] = 0.f;
    #pragma unroll
    for (int mm = 0; mm < 4; ++mm) {
        const float4* wr = (const float4*)&sWp[(sub + 8*mm)*36];
        float ov = o4[mm];
        #pragma unroll
        for (int dc = 0; dc < 8; ++dc) {
            float4 w4 = wr[dc];
            x1[4*dc]   = fmaf(ov, w4.x, x1[4*dc]);
            x1[4*dc+1] = fmaf(ov, w4.y, x1[4*dc+1]);
            x1[4*dc+2] = fmaf(ov, w4.z, x1[4*dc+2]);
            x1[4*dc+3] = fmaf(ov, w4.w, x1[4*dc+3]);
        }
    }
    #pragma unroll
    for (int d = 0; d < DD; ++d) {
        x1[d] += __shfl_xor(x1[d], 1, 64);
        x1[d] += __shfl_xor(x1[d], 2, 64);
        x1[d] += __shfl_xor(x1[d], 4, 64);
    }
    {
        const float4* hp = (const float4*)(h + (size_t)r * DD);
        #pragma unroll
        for (int dc = 0; dc < 8; ++dc) {
            float4 h4 = hp[dc];
            x1[4*dc]   += h4.x + sbp[4*dc];
            x1[4*dc+1] += h4.y + sbp[4*dc+1];
            x1[4*dc+2] += h4.z + sbp[4*dc+2];
            x1[4*dc+3] += h4.w + sbp[4*dc+3];
        }
    }
    float mu = 0.f;
    #pragma unroll
    for (int d = 0; d < DD; ++d) mu += x1[d];
    mu *= (1.f/DD);
    float var = 0.f;
    #pragma unroll
    for (int d = 0; d < DD; ++d) { float dl = x1[d]-mu; var += dl*dl; }
    var *= (1.f/DD);
    float rs = rsqrtf(var + LNEPS);
    float h2v[DD];
    #pragma unroll
    for (int d = 0; d < DD; ++d) h2v[d] = (x1[d]-mu)*rs*sg2[d] + sbt2[d];

    float outp[DD];
    #pragma unroll
    for (int d = 0; d < DD; ++d) outp[d] = 0.f;
    #pragma unroll
    for (int mm = 0; mm < 16; ++mm) {
        int j = sub + 8*mm;
        const float4* w1r = (const float4*)&sW1T[j*36];
        float a = sb1[j];
        #pragma unroll
        for (int dc = 0; dc < 8; ++dc) {
            float4 w4 = w1r[dc];
            a = fmaf(h2v[4*dc], w4.x, a);
            a = fmaf(h2v[4*dc+1], w4.y, a);
            a = fmaf(h2v[4*dc+2], w4.z, a);
            a = fmaf(h2v[4*dc+3], w4.w, a);
        }
        a = fmaxf(a, 0.f);
        const float4* w2r = (const float4*)&sW2[j*36];
        #pragma unroll
        for (int dc = 0; dc < 8; ++dc) {
            float4 w4 = w2r[dc];
            outp[4*dc]   = fmaf(a, w4.x, outp[4*dc]);
            outp[4*dc+1] = fmaf(a, w4.y, outp[4*dc+1]);
            outp[4*dc+2] = fmaf(a, w4.z, outp[4*dc+2]);
            outp[4*dc+3] = fmaf(a, w4.w, outp[4*dc+3]);
        }
    }
    if (sub == 0) {
        #pragma unroll
        for (int d = 0; d < DD; ++d) outp[d] += h2v[d] + sb2[d];
    }
    float t1[16];
    #pragma unroll
    for (int i = 0; i < 16; ++i) {
        bool hib = (sub & 4) != 0;
        float send = hib ? outp[i] : outp[i+16];
        float recv = __shfl_xor(send, 4, 64);
        t1[i] = (hib ? outp[i+16] : outp[i]) + recv;
    }
    float t2[8];
    #pragma unroll
    for (int i = 0; i < 8; ++i) {
        bool hib = (sub & 2) != 0;
        float send = hib ? t1[i] : t1[i+8];
        float recv = __shfl_xor(send, 2, 64);
        t2[i] = (hib ? t1[i+8] : t1[i]) + recv;
    }
    float w0[4];
    #pragma unroll
    for (int i = 0; i < 4; ++i) {
        bool hib = (sub & 1) != 0;
        float send = hib ? t2[i] : t2[i+4];
        float recv = __shfl_xor(send, 1, 64);
        w0[i] = (hib ? t2[i+4] : t2[i]) + recv;
    }
    *(float4*)(out + (size_t)r * DD + sub*4) = make_float4(w0[0], w0[1], w0[2], w0[3]);
}

extern "C" void kernel_launch(void* const* d_in, const int* in_sizes, int n_in,
                              void* d_out, int out_size, void* d_ws, size_t ws_size,
                              hipStream_t stream) {
    const float* x     = (const float*)d_in[0];
    const float* Wq    = (const float*)d_in[1];
    const float* Wk    = (const float*)d_in[2];
    const float* Wv    = (const float*)d_in[3];
    const float* Wproj = (const float*)d_in[4];
    const float* bproj = (const float*)d_in[5];
    const float* ln1_g = (const float*)d_in[6];
    const float* ln1_b = (const float*)d_in[7];
    const float* W1    = (const float*)d_in[8];
    const float* b1    = (const float*)d_in[9];
    const float* W2    = (const float*)d_in[10];
    const float* b2    = (const float*)d_in[11];
    const float* ln2_g = (const float*)d_in[12];
    const float* ln2_b = (const float*)d_in[13];
    float* out = (float*)d_out;

    const size_t N = (size_t)NROWS * DD;   // 524288
    const size_t K = (size_t)BB*HH*TT*4;   // 262144 floats = 1MB per buffer
    float* ws = (float*)d_ws;
    float* h  = ws;                        // N   f32
    float* qh = ws + N;                    // K   f16x8 per row (scaled by 1/sqrt(hd)*log2e)
    float* Kh = ws + N + K;                // K   f16 fragment-major [bh][plane][key][4]
    float* Vt = ws + N + 2*K;              // K   f16 transposed+swizzled [bh][d][tile][64]
    float* o  = ws + N + 3*K;              // N   f32 [bh][t][8]

    k_ln_qkv  <<<512, 256, 0, stream>>>(x, Wq, Wk, Wv, ln1_g, ln1_b, h, qh, Kh, Vt);
    k_attn    <<<1024, 256, 0, stream>>>(qh, Kh, Vt, o);
    k_proj_ffn<<<512, 256, 0, stream>>>(h, o, Wproj, bproj, W1, b1, W2, b2, ln2_g, ln2_b, out);
}

// Round 8
// 123.056 us; speedup vs baseline: 2.2154x; 1.1187x over previous
//
#include <hip/hip_runtime.h>
#include <math.h>

#define BB 8
#define TT 2048
#define DD 32
#define HH 4
#define HD 8
#define NROWS (BB*TT)       // 16384 (B*T); attention rows = B*H*T = 65536
#define LNEPS 1e-5f

#if __has_builtin(__builtin_amdgcn_exp2f)
#define EXP2F(x) __builtin_amdgcn_exp2f(x)
#else
#define EXP2F(x) __expf(0.6931471805599453f*(x))
#endif

typedef _Float16 h2 __attribute__((ext_vector_type(2)));
typedef _Float16 h4v __attribute__((ext_vector_type(4)));
typedef _Float16 h8v __attribute__((ext_vector_type(8)));
typedef float f32x16 __attribute__((ext_vector_type(16)));
struct KH { h2 a, b, c, d; };               // 16B: 8 halves
union F4H { float4 f; KH k; };

static __device__ __forceinline__ h2 pkrtz(float a, float b) {
    return __builtin_bit_cast(h2, __builtin_amdgcn_cvt_pkrtz(a, b));
}
static __device__ __forceinline__ unsigned pkrtz_u(float a, float b) {
    return __builtin_bit_cast(unsigned, __builtin_amdgcn_cvt_pkrtz(a, b));
}
static __device__ __forceinline__ unsigned short f16u(float x) {
    return __builtin_bit_cast(unsigned short, (_Float16)x);
}

#if __has_builtin(__builtin_amdgcn_fdot2)
#define DOT2(a,b,c) __builtin_amdgcn_fdot2((a),(b),(c),false)
#else
#define DOT2(a,b,c) fmaf((float)(a)[1],(float)(b)[1], fmaf((float)(a)[0],(float)(b)[0],(c)))
#endif

// ---------------- Kernel 1: LN1 + QKV projection (8 threads/row) ----------------
__global__ __launch_bounds__(256) void k_ln_qkv(
    const float* __restrict__ x,
    const float* __restrict__ Wq, const float* __restrict__ Wk, const float* __restrict__ Wv,
    const float* __restrict__ g, const float* __restrict__ b,
    float* __restrict__ h, float* __restrict__ qh,
    float* __restrict__ Kh, float* __restrict__ Vt)
{
    __shared__ float sW[3*HH*264];
    __shared__ float sg[DD], sb[DD];
    for (int i = threadIdx.x; i < HH*DD*HD; i += 256) {
        int hd_ = i >> 8, off = i & 255;
        sW[hd_*264 + off]              = Wq[i];
        sW[(4+hd_)*264 + off]          = Wk[i];
        sW[(8+hd_)*264 + off]          = Wv[i];
    }
    if (threadIdx.x < DD) { sg[threadIdx.x] = g[threadIdx.x]; sb[threadIdx.x] = b[threadIdx.x]; }
    __syncthreads();

    int idx = blockIdx.x * 256 + threadIdx.x;     // 0..131071
    int r   = idx >> 3;                           // row 0..16383
    int sub = idx & 7;
    int hh  = sub & 3;
    int dh  = sub >> 2;                           // 0/1 -> dims dh*16..+15
    int bb  = r >> 11, tt = r & 2047;

    float xr[16];
    {
        const float4* xp = (const float4*)(x + (size_t)r * DD + dh*16);
        float4 t0 = xp[0], t1 = xp[1], t2 = xp[2], t3 = xp[3];
        xr[0]=t0.x; xr[1]=t0.y; xr[2]=t0.z; xr[3]=t0.w;
        xr[4]=t1.x; xr[5]=t1.y; xr[6]=t1.z; xr[7]=t1.w;
        xr[8]=t2.x; xr[9]=t2.y; xr[10]=t2.z; xr[11]=t2.w;
        xr[12]=t3.x; xr[13]=t3.y; xr[14]=t3.z; xr[15]=t3.w;
    }
    float s1 = 0.f;
    #pragma unroll
    for (int i = 0; i < 16; ++i) s1 += xr[i];
    s1 += __shfl_xor(s1, 4, 64);
    float mu = s1 * (1.f/DD);
    float sq = 0.f;
    #pragma unroll
    for (int i = 0; i < 16; ++i) { float d = xr[i]-mu; sq += d*d; }
    sq += __shfl_xor(sq, 4, 64);
    float rs = rsqrtf(sq * (1.f/DD) + LNEPS);

    float hr[16];
    #pragma unroll
    for (int i = 0; i < 16; ++i) hr[i] = (xr[i]-mu)*rs*sg[dh*16+i] + sb[dh*16+i];

    {
        float4* hp = (float4*)(h + (size_t)r * DD + dh*16);
        hp[0]=make_float4(hr[0],hr[1],hr[2],hr[3]);
        hp[1]=make_float4(hr[4],hr[5],hr[6],hr[7]);
        hp[2]=make_float4(hr[8],hr[9],hr[10],hr[11]);
        hp[3]=make_float4(hr[12],hr[13],hr[14],hr[15]);
    }

    const float* wq = sW + hh*264 + dh*128;
    const float* wk = sW + (4+hh)*264 + dh*128;
    const float* wv = sW + (8+hh)*264 + dh*128;
    float qa[HD], ka[HD], va[HD];
    #pragma unroll
    for (int k2 = 0; k2 < HD; ++k2) { qa[k2]=0.f; ka[k2]=0.f; va[k2]=0.f; }
    #pragma unroll
    for (int d = 0; d < 16; ++d) {
        float hv = hr[d];
        const float4* wq4 = (const float4*)(wq + d*8);
        const float4* wk4 = (const float4*)(wk + d*8);
        const float4* wv4 = (const float4*)(wv + d*8);
        float4 a0 = wq4[0], a1 = wq4[1];
        float4 b0 = wk4[0], b1 = wk4[1];
        float4 c0 = wv4[0], c1 = wv4[1];
        qa[0]=fmaf(hv,a0.x,qa[0]); qa[1]=fmaf(hv,a0.y,qa[1]); qa[2]=fmaf(hv,a0.z,qa[2]); qa[3]=fmaf(hv,a0.w,qa[3]);
        qa[4]=fmaf(hv,a1.x,qa[4]); qa[5]=fmaf(hv,a1.y,qa[5]); qa[6]=fmaf(hv,a1.z,qa[6]); qa[7]=fmaf(hv,a1.w,qa[7]);
        ka[0]=fmaf(hv,b0.x,ka[0]); ka[1]=fmaf(hv,b0.y,ka[1]); ka[2]=fmaf(hv,b0.z,ka[2]); ka[3]=fmaf(hv,b0.w,ka[3]);
        ka[4]=fmaf(hv,b1.x,ka[4]); ka[5]=fmaf(hv,b1.y,ka[5]); ka[6]=fmaf(hv,b1.z,ka[6]); ka[7]=fmaf(hv,b1.w,ka[7]);
        va[0]=fmaf(hv,c0.x,va[0]); va[1]=fmaf(hv,c0.y,va[1]); va[2]=fmaf(hv,c0.z,va[2]); va[3]=fmaf(hv,c0.w,va[3]);
        va[4]=fmaf(hv,c1.x,va[4]); va[5]=fmaf(hv,c1.y,va[5]); va[6]=fmaf(hv,c1.z,va[6]); va[7]=fmaf(hv,c1.w,va[7]);
    }
    #pragma unroll
    for (int k2 = 0; k2 < HD; ++k2) {
        qa[k2] += __shfl_xor(qa[k2], 4, 64);
        ka[k2] += __shfl_xor(ka[k2], 4, 64);
        va[k2] += __shfl_xor(va[k2], 4, 64);
    }

    const float SCL = 0.35355339059327373f * 1.4426950408889634f;  // 1/sqrt(8)*log2e
    size_t key = (size_t)(bb*HH + hh)*TT + tt;
    unsigned short* vtb = (unsigned short*)Vt + (size_t)(bb*HH + hh)*8*TT + tt;
    if (dh == 0) {
        F4H u;
        u.k.a = pkrtz(qa[0]*SCL, qa[1]*SCL);
        u.k.b = pkrtz(qa[2]*SCL, qa[3]*SCL);
        u.k.c = pkrtz(qa[4]*SCL, qa[5]*SCL);
        u.k.d = pkrtz(qa[6]*SCL, qa[7]*SCL);
        *(float4*)(qh + key*4) = u.f;
        vtb[(size_t)0*TT] = f16u(va[0]);
        vtb[(size_t)1*TT] = f16u(va[1]);
        vtb[(size_t)2*TT] = f16u(va[2]);
        vtb[(size_t)3*TT] = f16u(va[3]);
    } else {
        // K fragment-major: plane0 = halves 0-3, plane1 = halves 4-7
        char* Kb8 = (char*)Kh + (size_t)(bb*HH + hh)*32768;
        uint2 k01; k01.x = pkrtz_u(ka[0],ka[1]); k01.y = pkrtz_u(ka[2],ka[3]);
        uint2 k23; k23.x = pkrtz_u(ka[4],ka[5]); k23.y = pkrtz_u(ka[6],ka[7]);
        *(uint2*)(Kb8 + (size_t)tt*8) = k01;
        *(uint2*)(Kb8 + 16384 + (size_t)tt*8) = k23;
        vtb[(size_t)4*TT] = f16u(va[4]);
        vtb[(size_t)5*TT] = f16u(va[5]);
        vtb[(size_t)6*TT] = f16u(va[6]);
        vtb[(size_t)7*TT] = f16u(va[7]);
    }
}

// ---------------- Kernel 2: 32x32 MFMA flash attention, barrier-free main loop ----
// Wave = 32 queries, parity-split key range; operands loaded DIRECTLY from L2
// (no LDS staging, no per-tile barriers), software-pipelined 1 chunk ahead.
template<bool DIAG>
__device__ __forceinline__ void chunk_compute(
    uint2 kraw, uint4 v0r, uint4 v1r, int hi, int col,
    h4v qf, float& m, float& l, f32x16& acc)
{
    h4v kf = __builtin_bit_cast(h4v, kraw);
    f32x16 cin;
    #pragma unroll
    for (int r2 = 0; r2 < 16; ++r2) cin[r2] = -m;
    f32x16 S = __builtin_amdgcn_mfma_f32_32x32x8f16(kf, qf, cin, 0, 0, 0);
    if (DIAG) {
        #pragma unroll
        for (int r2 = 0; r2 < 16; ++r2) {
            int row = (r2&3) + 8*(r2>>2) + 4*hi;
            if (row > col) S[r2] = -1e30f;
        }
    }
    float pm = S[0];
    #pragma unroll
    for (int r2 = 1; r2 < 16; ++r2) pm = fmaxf(pm, S[r2]);
    pm = fmaxf(pm, __shfl_xor(pm, 32, 64));
    if (__builtin_expect(__any(pm > 8.f), 0)) {       // defer-max: rare rescale
        float adj = fmaxf(pm, 0.f);
        float cr  = EXP2F(-adj);
        l *= cr;
        #pragma unroll
        for (int r2 = 0; r2 < 16; ++r2) {
            int row = (r2&3) + 8*(r2>>2) + 4*hi;
            acc[r2] *= __shfl(cr, row, 64);
        }
        #pragma unroll
        for (int r2 = 0; r2 < 16; ++r2) S[r2] -= adj;
        m += adj;
    }
    float p[16];
    #pragma unroll
    for (int r2 = 0; r2 < 16; ++r2) p[r2] = EXP2F(S[r2]);
    unsigned pa_ = pkrtz_u(p[0],  p[1]);
    unsigned pb_ = pkrtz_u(p[2],  p[3]);
    unsigned pc_ = pkrtz_u(p[4],  p[5]);
    unsigned pd_ = pkrtz_u(p[6],  p[7]);
    unsigned pe_ = pkrtz_u(p[8],  p[9]);
    unsigned pf_ = pkrtz_u(p[10], p[11]);
    unsigned pg_ = pkrtz_u(p[12], p[13]);
    unsigned ph_ = pkrtz_u(p[14], p[15]);
    const h2 one2 = {(_Float16)1.f, (_Float16)1.f};
    l = DOT2(__builtin_bit_cast(h2, pa_), one2, l);
    l = DOT2(__builtin_bit_cast(h2, pb_), one2, l);
    l = DOT2(__builtin_bit_cast(h2, pc_), one2, l);
    l = DOT2(__builtin_bit_cast(h2, pd_), one2, l);
    l = DOT2(__builtin_bit_cast(h2, pe_), one2, l);
    l = DOT2(__builtin_bit_cast(h2, pf_), one2, l);
    l = DOT2(__builtin_bit_cast(h2, pg_), one2, l);
    l = DOT2(__builtin_bit_cast(h2, ph_), one2, l);
    unsigned ra = (unsigned)__shfl_xor((int)pa_, 32, 64);
    unsigned rb = (unsigned)__shfl_xor((int)pb_, 32, 64);
    unsigned rc = (unsigned)__shfl_xor((int)pc_, 32, 64);
    unsigned rd = (unsigned)__shfl_xor((int)pd_, 32, 64);
    unsigned re = (unsigned)__shfl_xor((int)pe_, 32, 64);
    unsigned rf = (unsigned)__shfl_xor((int)pf_, 32, 64);
    unsigned rg = (unsigned)__shfl_xor((int)pg_, 32, 64);
    unsigned rh = (unsigned)__shfl_xor((int)ph_, 32, 64);
    bool H = (hi != 0);
    uint4 A0 = { H?rc:pa_, H?rd:pb_, H?pc_:ra, H?pd_:rb };   // PV keys +0..15
    uint4 A1 = { H?rg:pe_, H?rh:pf_, H?pg_:re, H?ph_:rf };   // PV keys +16..31
    acc = __builtin_amdgcn_mfma_f32_32x32x16_f16(
        __builtin_bit_cast(h8v, A0), __builtin_bit_cast(h8v, v0r), acc, 0, 0, 0);
    acc = __builtin_amdgcn_mfma_f32_32x32x16_f16(
        __builtin_bit_cast(h8v, A1), __builtin_bit_cast(h8v, v1r), acc, 0, 0, 0);
}

__global__ __launch_bounds__(256) void k_attn(
    const float* __restrict__ qh, const float* __restrict__ Kh,
    const float* __restrict__ Vt, float* __restrict__ o)
{
    __shared__ float mb[128];     // [tl*64 + p*32 + col]
    __shared__ float lb[128];
    __shared__ float ob[512];     // [tl*256 + row*8 + col]
    const int tid  = threadIdx.x;
    const int wave = tid >> 6;
    const int lane = tid & 63;
    const int hi   = lane >> 5;
    const int col  = lane & 31;
    const int tl   = wave >> 1;               // tile slot in block (0/1)
    const int p    = wave & 1;                // key parity
    const int T    = blockIdx.x * 2 + tl;     // global tile id 0..2047
    const int qi   = 63 - (T >> 5);           // q-tile index (heavy first)
    const int bh   = T & 31;
    const int wq0  = qi << 5;

    const char* Kg = (const char*)Kh + (size_t)bh * 32768;   // [plane][2048 keys][8B]
    const char* Vg = (const char*)Vt + (size_t)bh * 32768;   // V^T [8 d][2048 keys]*2B
    const char* Qg = (const char*)qh + (size_t)bh * 32768 + (size_t)wq0 * 16;
    const char* vrow = Vg + (size_t)(col & 7) * 4096;

    // Q B-frag: col = query, k = 4*hi + i
    h4v qf = __builtin_bit_cast(h4v, *(const uint2*)(Qg + col*16 + hi*8));

    f32x16 acc;
    #pragma unroll
    for (int r2 = 0; r2 < 16; ++r2) acc[r2] = 0.f;
    float m = 0.f, l = 0.f;

#define LOADC(c, K2, V0, V1) do { \
    K2 = *(const uint2*)(Kg + hi*16384 + (size_t)((((c)<<5) + col))*8); \
    V0 = *(const uint4*)(vrow + (size_t)((((c)<<5) + (hi<<3)))*2); \
    V1 = *(const uint4*)(vrow + (size_t)((((c)<<5) + 16 + (hi<<3)))*2); \
} while (0)

    const int last = ((qi & 1) == p) ? qi : qi - 1;   // this parity's last chunk
    if (last >= p) {
        uint2 kc_; uint4 v0c, v1c;
        LOADC(p, kc_, v0c, v1c);
        int c = p;
        while (c < last) {
            uint2 kn_; uint4 v0n, v1n;
            LOADC(c + 2, kn_, v0n, v1n);
            chunk_compute<false>(kc_, v0c, v1c, hi, col, qf, m, l, acc);
            kc_ = kn_; v0c = v0n; v1c = v1n;
            c += 2;
        }
        if (last == qi) chunk_compute<true >(kc_, v0c, v1c, hi, col, qf, m, l, acc);
        else            chunk_compute<false>(kc_, v0c, v1c, hi, col, qf, m, l, acc);
    }
#undef LOADC

    // ---- merge the two key-parity waves of this tile ----
    l += __shfl_xor(l, 32, 64);               // combine hi halves per query
    if (lane < 32) {
        mb[tl*64 + p*32 + col] = m;
        lb[tl*64 + p*32 + col] = l;
    }
    __syncthreads();
    float mo = mb[tl*64 + (p^1)*32 + col];
    float lo = lb[tl*64 + (p^1)*32 + col];
    float M  = fmaxf(m, mo);
    float fs = EXP2F(m - M);
    float L  = l * fs + lo * EXP2F(mo - M);
    float Linv = 1.f / L;
    float fr[16], Lr[16];
    #pragma unroll
    for (int r2 = 0; r2 < 16; ++r2) {
        int row = (r2&3) + 8*(r2>>2) + 4*hi;
        fr[r2] = __shfl(fs,   row, 64);
        Lr[r2] = __shfl(Linv, row, 64);
    }
    if (p == 1 && col < HD) {
        #pragma unroll
        for (int r2 = 0; r2 < 16; ++r2) {
            int row = (r2&3) + 8*(r2>>2) + 4*hi;
            ob[tl*256 + (row<<3) + col] = acc[r2] * fr[r2];
        }
    }
    __syncthreads();
    if (p == 0 && col < HD) {
        float* og = o + ((size_t)bh*TT + wq0)*HD + col;
        #pragma unroll
        for (int r2 = 0; r2 < 16; ++r2) {
            int row = (r2&3) + 8*(r2>>2) + 4*hi;
            og[(size_t)row * HD] = (acc[r2]*fr[r2] + ob[tl*256 + (row<<3) + col]) * Lr[r2];
        }
    }
}

// ---------------- Kernel 3: proj + residual + LN2 + FFN (8 threads/row) ----------
__global__ __launch_bounds__(256) void k_proj_ffn(
    const float* __restrict__ h, const float* __restrict__ o,
    const float* __restrict__ Wproj, const float* __restrict__ bproj,
    const float* __restrict__ W1, const float* __restrict__ b1,
    const float* __restrict__ W2, const float* __restrict__ b2,
    const float* __restrict__ g2, const float* __restrict__ bt2,
    float* __restrict__ out)
{
    __shared__ float sWp[DD*36], sW1T[4*DD*36], sW2[4*DD*36];
    __shared__ float sbp[DD], sb1[4*DD], sb2[DD], sg2[DD], sbt2[DD];
    for (int i = threadIdx.x; i < DD*DD; i += 256)      sWp [(i>>5)*36 + (i&31)] = Wproj[i];
    for (int i = threadIdx.x; i < DD*4*DD; i += 256) {
        sW1T[(i&127)*36 + (i>>7)] = W1[i];
        sW2 [(i>>5)*36 + (i&31)]  = W2[i];
    }
    if (threadIdx.x < DD) {
        sbp[threadIdx.x]  = bproj[threadIdx.x];
        sb2[threadIdx.x]  = b2[threadIdx.x];
        sg2[threadIdx.x]  = g2[threadIdx.x];
        sbt2[threadIdx.x] = bt2[threadIdx.x];
    }
    if (threadIdx.x < 4*DD) sb1[threadIdx.x] = b1[threadIdx.x];
    __syncthreads();

    int idx = blockIdx.x * 256 + threadIdx.x;
    int r   = idx >> 3;
    int sub = idx & 7;
    int bb  = r >> 11, tt = r & 2047;

    float o4[4];
    #pragma unroll
    for (int mm = 0; mm < 4; ++mm)
        o4[mm] = o[((size_t)(bb*HH + mm)*TT + tt) * HD + sub];

    float x1[DD];
    #pragma unroll
    for (int d = 0; d < DD; ++d) x1[d] = 0.f;
    #pragma unroll
    for (int mm = 0; mm < 4; ++mm) {
        const float4* wr = (const float4*)&sWp[(sub + 8*mm)*36];
        float ov = o4[mm];
        #pragma unroll
        for (int dc = 0; dc < 8; ++dc) {
            float4 w4 = wr[dc];
            x1[4*dc]   = fmaf(ov, w4.x, x1[4*dc]);
            x1[4*dc+1] = fmaf(ov, w4.y, x1[4*dc+1]);
            x1[4*dc+2] = fmaf(ov, w4.z, x1[4*dc+2]);
            x1[4*dc+3] = fmaf(ov, w4.w, x1[4*dc+3]);
        }
    }
    #pragma unroll
    for (int d = 0; d < DD; ++d) {
        x1[d] += __shfl_xor(x1[d], 1, 64);
        x1[d] += __shfl_xor(x1[d], 2, 64);
        x1[d] += __shfl_xor(x1[d], 4, 64);
    }
    {
        const float4* hp = (const float4*)(h + (size_t)r * DD);
        #pragma unroll
        for (int dc = 0; dc < 8; ++dc) {
            float4 h4 = hp[dc];
            x1[4*dc]   += h4.x + sbp[4*dc];
            x1[4*dc+1] += h4.y + sbp[4*dc+1];
            x1[4*dc+2] += h4.z + sbp[4*dc+2];
            x1[4*dc+3] += h4.w + sbp[4*dc+3];
        }
    }
    float mu = 0.f;
    #pragma unroll
    for (int d = 0; d < DD; ++d) mu += x1[d];
    mu *= (1.f/DD);
    float var = 0.f;
    #pragma unroll
    for (int d = 0; d < DD; ++d) { float dl = x1[d]-mu; var += dl*dl; }
    var *= (1.f/DD);
    float rs = rsqrtf(var + LNEPS);
    float h2v[DD];
    #pragma unroll
    for (int d = 0; d < DD; ++d) h2v[d] = (x1[d]-mu)*rs*sg2[d] + sbt2[d];

    float outp[DD];
    #pragma unroll
    for (int d = 0; d < DD; ++d) outp[d] = 0.f;
    #pragma unroll
    for (int mm = 0; mm < 16; ++mm) {
        int j = sub + 8*mm;
        const float4* w1r = (const float4*)&sW1T[j*36];
        float a = sb1[j];
        #pragma unroll
        for (int dc = 0; dc < 8; ++dc) {
            float4 w4 = w1r[dc];
            a = fmaf(h2v[4*dc], w4.x, a);
            a = fmaf(h2v[4*dc+1], w4.y, a);
            a = fmaf(h2v[4*dc+2], w4.z, a);
            a = fmaf(h2v[4*dc+3], w4.w, a);
        }
        a = fmaxf(a, 0.f);
        const float4* w2r = (const float4*)&sW2[j*36];
        #pragma unroll
        for (int dc = 0; dc < 8; ++dc) {
            float4 w4 = w2r[dc];
            outp[4*dc]   = fmaf(a, w4.x, outp[4*dc]);
            outp[4*dc+1] = fmaf(a, w4.y, outp[4*dc+1]);
            outp[4*dc+2] = fmaf(a, w4.z, outp[4*dc+2]);
            outp[4*dc+3] = fmaf(a, w4.w, outp[4*dc+3]);
        }
    }
    if (sub == 0) {
        #pragma unroll
        for (int d = 0; d < DD; ++d) outp[d] += h2v[d] + sb2[d];
    }
    float t1[16];
    #pragma unroll
    for (int i = 0; i < 16; ++i) {
        bool hib = (sub & 4) != 0;
        float send = hib ? outp[i] : outp[i+16];
        float recv = __shfl_xor(send, 4, 64);
        t1[i] = (hib ? outp[i+16] : outp[i]) + recv;
    }
    float t2[8];
    #pragma unroll
    for (int i = 0; i < 8; ++i) {
        bool hib = (sub & 2) != 0;
        float send = hib ? t1[i] : t1[i+8];
        float recv = __shfl_xor(send, 2, 64);
        t2[i] = (hib ? t1[i+8] : t1[i]) + recv;
    }
    float w0[4];
    #pragma unroll
    for (int i = 0; i < 4; ++i) {
        bool hib = (sub & 1) != 0;
        float send = hib ? t2[i] : t2[i+4];
        float recv = __shfl_xor(send, 1, 64);
        w0[i] = (hib ? t2[i+4] : t2[i]) + recv;
    }
    *(float4*)(out + (size_t)r * DD + sub*4) = make_float4(w0[0], w0[1], w0[2], w0[3]);
}

extern "C" void kernel_launch(void* const* d_in, const int* in_sizes, int n_in,
                              void* d_out, int out_size, void* d_ws, size_t ws_size,
                              hipStream_t stream) {
    const float* x     = (const float*)d_in[0];
    const float* Wq    = (const float*)d_in[1];
    const float* Wk    = (const float*)d_in[2];
    const float* Wv    = (const float*)d_in[3];
    const float* Wproj = (const float*)d_in[4];
    const float* bproj = (const float*)d_in[5];
    const float* ln1_g = (const float*)d_in[6];
    const float* ln1_b = (const float*)d_in[7];
    const float* W1    = (const float*)d_in[8];
    const float* b1    = (const float*)d_in[9];
    const float* W2    = (const float*)d_in[10];
    const float* b2    = (const float*)d_in[11];
    const float* ln2_g = (const float*)d_in[12];
    const float* ln2_b = (const float*)d_in[13];
    float* out = (float*)d_out;

    const size_t N = (size_t)NROWS * DD;   // 524288
    const size_t K = (size_t)BB*HH*TT*4;   // 262144 floats = 1MB per buffer
    float* ws = (float*)d_ws;
    float* h  = ws;                        // N   f32
    float* qh = ws + N;                    // K   f16x8 per row (scaled by 1/sqrt(hd)*log2e)
    float* Kh = ws + N + K;                // K   f16 fragment-major [bh][plane][key][4]
    float* Vt = ws + N + 2*K;              // K   f16 plain V^T [bh][d][t]
    float* o  = ws + N + 3*K;              // N   f32 [bh][t][8]

    k_ln_qkv  <<<512, 256, 0, stream>>>(x, Wq, Wk, Wv, ln1_g, ln1_b, h, qh, Kh, Vt);
    k_attn    <<<1024, 256, 0, stream>>>(qh, Kh, Vt, o);
    k_proj_ffn<<<512, 256, 0, stream>>>(h, o, Wproj, bproj, W1, b1, W2, b2, ln2_g, ln2_b, out);
}